// Round 7
// baseline (1947.330 us; speedup 1.0000x reference)
//
#include <hip/hip_runtime.h>
#include <hip/hip_bf16.h>

// CYK forward. p-chain fp32; f-chain GEMM bf16x3 MFMA.
// Round 14 (= round 13 + coverage fix): phase rebalance + setup merge +
// combine h-split.
//   X(ln) = scores(ln) || outer(ln+1) || combine(ln)   [streams + fp32 GEMM]
//   Y(ln) = normp(ln)  || uv(diag ln-1)                [MFMA + light reduce]
// FIX vs round 13: diag_v role (diag-0 chart_v) was launched with 512
// blocks = 1024 cells, but diag 0 has 2048 cells -> chart_v for batches
// 32-63 kept harness poison -> absmax 5e-4. Grid is now 1024 blocks.
// combine split 2 blocks/row (256 h-cols each) for late-diagonal fill.
// S1 = prep_g||prep_wmt||diag_p||feat0; S2 = prep_e||prep_f||uv(diag0)||
// outer(ln=2)||diag_v. 65 dispatches total.

typedef __attribute__((ext_vector_type(8))) short short8;
typedef __attribute__((ext_vector_type(4))) float f32x4;

constexpr int cB = 64, cL = 32, cNT = 64, cS = 128, cV = 50000;
constexpr int cEMB = 512, cSD = 512, cKQ = 4096; // quadrant k
constexpr int DMAX = 31, KS = 16;                // k-slice = 256
constexpr int CHpad = 1984;
constexpr float cEPS = 1e-9f;
constexpr long TRIC = (long)cB * (cL * (cL + 1) / 2); // 33792 packed cells

__device__ __forceinline__ long dBase(int d) {
  return (long)cB * ((long)d * cL - ((long)d * (d - 1)) / 2);
}

__device__ __forceinline__ void split_bf16(float x, __hip_bfloat16& h, __hip_bfloat16& l) {
  h = __float2bfloat16(x);
  l = __float2bfloat16(x - __bfloat162float(h));
}

// ---------------- fp32 GEMM micro ----------------
__device__ __forceinline__ void micro16(const float (*As)[68], const float (*Bs)[68],
                                        int r0, int c0, float acc[4][4]) {
  #pragma unroll
  for (int k = 0; k < 16; ++k) {
    float4 a4 = *(const float4*)&As[k][r0];
    float4 b4 = *(const float4*)&Bs[k][c0];
    float ar[4] = {a4.x, a4.y, a4.z, a4.w};
    float br[4] = {b4.x, b4.y, b4.z, b4.w};
    #pragma unroll
    for (int i = 0; i < 4; ++i)
      #pragma unroll
      for (int j = 0; j < 4; ++j)
        acc[i][j] = fmaf(ar[i], br[j], acc[i][j]);
  }
}

// ---------------- uv GEMM body (bf16x3 MFMA, 128x128 tile, K=512) ----------------
__device__ __forceinline__ void uv_body(
    char* smraw, int tid, int ubid,
    const __hip_bfloat16* __restrict__ cfh, const __hip_bfloat16* __restrict__ cfl,
    const __hip_bfloat16* __restrict__ WmTh, const __hip_bfloat16* __restrict__ WmTl,
    float* __restrict__ uv, long cellBase, int M) {
  short* Ash = (short*)smraw;              // [2*128][40]
  short* Bsh = (short*)(smraw + 20480);    // [2*128][40]
  int colTile = (ubid & 7) << 7;
  int rowTile = (ubid >> 3) << 7;
  int m0 = tid >> 2, kq8 = (tid & 3) * 8;

  long offA[2];
  #pragma unroll
  for (int h = 0; h < 2; ++h) {
    int row = rowTile + m0 + h * 64;
    if (row >= M) row = M - 1;
    offA[h] = (cellBase + row) * cSD;
  }
  long offB0 = (long)(colTile + m0) * 512;
  long offB1 = (long)(colTile + m0 + 64) * 512;

  f32x4 acc[4][4];
  f32x4 zero = {0.f, 0.f, 0.f, 0.f};
  #pragma unroll
  for (int a_ = 0; a_ < 4; ++a_)
    #pragma unroll
    for (int b_ = 0; b_ < 4; ++b_) acc[a_][b_] = zero;

  int lane = tid & 63, wid = tid >> 6;
  int wm = wid >> 1, wn = wid & 1;
  int fr = lane & 15, fq = lane >> 4;

  int4 pA0h = *(const int4*)(const void*)(cfh + offA[0] + kq8);
  int4 pA1h = *(const int4*)(const void*)(cfh + offA[1] + kq8);
  int4 pA0l = *(const int4*)(const void*)(cfl + offA[0] + kq8);
  int4 pA1l = *(const int4*)(const void*)(cfl + offA[1] + kq8);
  int4 pB0h = *(const int4*)(const void*)(WmTh + offB0 + kq8);
  int4 pB1h = *(const int4*)(const void*)(WmTh + offB1 + kq8);
  int4 pB0l = *(const int4*)(const void*)(WmTl + offB0 + kq8);
  int4 pB1l = *(const int4*)(const void*)(WmTl + offB1 + kq8);

  for (int kb = 0; kb < 512; kb += 32) {
    __syncthreads();
    *(int4*)&Ash[(0 * 128 + m0) * 40 + kq8] = pA0h;
    *(int4*)&Ash[(0 * 128 + m0 + 64) * 40 + kq8] = pA1h;
    *(int4*)&Ash[(1 * 128 + m0) * 40 + kq8] = pA0l;
    *(int4*)&Ash[(1 * 128 + m0 + 64) * 40 + kq8] = pA1l;
    *(int4*)&Bsh[(0 * 128 + m0) * 40 + kq8] = pB0h;
    *(int4*)&Bsh[(0 * 128 + m0 + 64) * 40 + kq8] = pB1h;
    *(int4*)&Bsh[(1 * 128 + m0) * 40 + kq8] = pB0l;
    *(int4*)&Bsh[(1 * 128 + m0 + 64) * 40 + kq8] = pB1l;
    __syncthreads();
    int kn = kb + 32;
    if (kn < 512) {
      pA0h = *(const int4*)(const void*)(cfh + offA[0] + kn + kq8);
      pA1h = *(const int4*)(const void*)(cfh + offA[1] + kn + kq8);
      pA0l = *(const int4*)(const void*)(cfl + offA[0] + kn + kq8);
      pA1l = *(const int4*)(const void*)(cfl + offA[1] + kn + kq8);
      pB0h = *(const int4*)(const void*)(WmTh + offB0 + kn + kq8);
      pB1h = *(const int4*)(const void*)(WmTh + offB1 + kn + kq8);
      pB0l = *(const int4*)(const void*)(WmTl + offB0 + kn + kq8);
      pB1l = *(const int4*)(const void*)(WmTl + offB1 + kn + kq8);
    }
    short8 af[2][4], bf[2][4];
    #pragma unroll
    for (int pl = 0; pl < 2; ++pl)
      #pragma unroll
      for (int mf = 0; mf < 4; ++mf)
        af[pl][mf] = *(const short8*)&Ash[(pl * 128 + wm * 64 + mf * 16 + fr) * 40 + fq * 8];
    #pragma unroll
    for (int pl = 0; pl < 2; ++pl)
      #pragma unroll
      for (int nf = 0; nf < 4; ++nf)
        bf[pl][nf] = *(const short8*)&Bsh[(pl * 128 + wn * 64 + nf * 16 + fr) * 40 + fq * 8];
    #pragma unroll
    for (int mf = 0; mf < 4; ++mf)
      #pragma unroll
      for (int nf = 0; nf < 4; ++nf) {
        acc[mf][nf] = __builtin_amdgcn_mfma_f32_16x16x32_bf16(af[0][mf], bf[0][nf], acc[mf][nf], 0, 0, 0);
        acc[mf][nf] = __builtin_amdgcn_mfma_f32_16x16x32_bf16(af[0][mf], bf[1][nf], acc[mf][nf], 0, 0, 0);
        acc[mf][nf] = __builtin_amdgcn_mfma_f32_16x16x32_bf16(af[1][mf], bf[0][nf], acc[mf][nf], 0, 0, 0);
      }
  }
  #pragma unroll
  for (int mf = 0; mf < 4; ++mf)
    #pragma unroll
    for (int r = 0; r < 4; ++r) {
      int row = rowTile + wm * 64 + mf * 16 + fq * 4 + r;
      if (row >= M) continue;
      float* op = uv + (cellBase + row) * 1024 + colTile + wn * 64;
      #pragma unroll
      for (int nf = 0; nf < 4; ++nf)
        op[nf * 16 + fr] = acc[mf][nf][r];
    }
}

// ---------------- outer-product body ----------------
__device__ __forceinline__ void outer_body(
    char* smraw, int tid, int lr, const float* __restrict__ chart_p,
    float* __restrict__ Oout, int oln, int on, int odlo, int odhi,
    int osoff, int otoff) {
  float* lp = (float*)smraw;                  // [DMAX][64]
  float* rp = (float*)(smraw + DMAX * 64 * 4);
  int b = lr / on, i = lr - b * on;
  if (tid < 128) {
    int lane = tid & 63;
    for (int dd = odlo + (tid >> 6); dd <= odhi; dd += 2) {
      long lc = dBase(dd) + (long)b * (cL - dd) + i;
      lp[(dd - odlo) * 64 + lane] = chart_p[lc * cS + osoff + lane];
    }
  } else {
    int t2 = tid - 128;
    int lane = t2 & 63;
    for (int dd = odlo + (t2 >> 6); dd <= odhi; dd += 2) {
      int dr = oln - dd - 2;
      long rc = dBase(dr) + (long)b * (cL - dr) + (i + dd + 1);
      rp[(dd - odlo) * 64 + lane] = chart_p[rc * cS + otoff + lane];
    }
  }
  __syncthreads();
  float acc[16];
  #pragma unroll
  for (int j = 0; j < 16; ++j) acc[j] = 0.f;
  int s = tid >> 2, t0 = (tid & 3) << 4;
  int dcount = odhi - odlo + 1;
  for (int dd = 0; dd < dcount; ++dd) {
    float lps = lp[dd * 64 + s];
    #pragma unroll
    for (int qq = 0; qq < 4; ++qq) {
      float4 r4 = *(const float4*)&rp[dd * 64 + t0 + qq * 4];
      acc[qq * 4 + 0] = fmaf(lps, r4.x, acc[qq * 4 + 0]);
      acc[qq * 4 + 1] = fmaf(lps, r4.y, acc[qq * 4 + 1]);
      acc[qq * 4 + 2] = fmaf(lps, r4.z, acc[qq * 4 + 2]);
      acc[qq * 4 + 3] = fmaf(lps, r4.w, acc[qq * 4 + 3]);
    }
  }
  float* op = Oout + (size_t)lr * cKQ + (size_t)tid * 16; // p = s*64+t
  #pragma unroll
  for (int j = 0; j < 4; ++j) {
    float4 o = {acc[j * 4 + 0], acc[j * 4 + 1], acc[j * 4 + 2], acc[j * 4 + 3]};
    *(float4*)&op[j * 4] = o;
  }
}

// ---------------- S1: prep_g || prep_wmt || diag_p || feat0 ----------------
// diag role writes chart_p ONLY (chart_v for diag 0 is computed in S2's
// diag_v role -- GsumT is written by prep_g in THIS kernel; no intra-kernel
// inter-block ordering exists).
__global__ __launch_bounds__(256) void k_S1(
    const float* __restrict__ G, float* __restrict__ Gll, float* __restrict__ Ghh,
    float* __restrict__ GsumT, const float* __restrict__ Wm,
    __hip_bfloat16* __restrict__ WmTh, __hip_bfloat16* __restrict__ WmTl,
    const int* __restrict__ word, const float* __restrict__ preterm,
    float* __restrict__ chart_p,
    const float* __restrict__ WE, const float* __restrict__ Wp,
    const float* __restrict__ bp,
    __hip_bfloat16* __restrict__ cfh, __hip_bfloat16* __restrict__ cfl) {
  __shared__ __align__(16) char smraw[8704];
  int bid = blockIdx.x, tid = threadIdx.x;
  if (bid < 64) {
    // prep_g
    int idx = bid * 256 + tid; // s*128+t
    int s = idx >> 7, t = idx & 127;
    bool lo = (s < 64) && (t < 64);
    bool hi = (s >= 64) && (t >= 64);
    int pl = s * 64 + t;
    int ph = (s - 64) * 64 + (t - 64);
    float accum = 0.f;
    for (int a = 0; a < cNT; ++a) {
      float g = G[(size_t)a * 16384 + idx];
      accum += g;
      if (lo) Gll[(size_t)pl * cNT + a] = g;
      if (hi) Ghh[(size_t)ph * cNT + a] = g;
    }
    GsumT[t * cS + s] = accum;
  } else if (bid < 64 + 2048) {
    // prep_wmt: layout [nn<1024][k<512]
    int idx = (bid - 64) * 256 + tid; // nn*512 + k
    int k = idx & 511, nn = idx >> 9;
    int krow = k + ((nn >= 512) ? 512 : 0);
    float v = Wm[(size_t)krow * cSD + (nn & 511)];
    __hip_bfloat16 h, l;
    split_bf16(v, h, l);
    WmTh[idx] = h;
    WmTl[idx] = l;
  } else if (bid < 64 + 2048 + 1024) {
    // diag_p: 2 cells per block; chart_p only
    int dbid = bid - (64 + 2048);
    int rsel = tid >> 7, t = tid & 127;
    int r2 = dbid * 2 + rsel;
    int w = word[r2];
    float val = (t >= 64) ? preterm[(size_t)(t - 64) * cV + w] : 0.f;
    float sum = val;
    #pragma unroll
    for (int off = 1; off < 64; off <<= 1) sum += __shfl_xor(sum, off, 64);
    float p_ = (t >= 64) ? val / (sum + cEPS) : 0.f;
    chart_p[(size_t)r2 * cS + t] = p_;
  } else {
    // feat0
    float (*As)[68] = (float (*)[68])smraw;
    float (*Bs)[68] = (float (*)[68])(smraw + 4352);
    int fb = bid - (64 + 2048 + 1024);
    int rowTile = (fb >> 3) * 64;
    int n0 = (fb & 7) * 64;
    int lr = tid >> 2, lk = (tid & 3) << 2;
    int bk = tid >> 4, bn = (tid & 15) << 2;
    int r0 = (tid >> 4) << 2, c0 = (tid & 15) << 2;
    const float* ap = WE + (size_t)word[rowTile + lr] * cEMB;
    float acc[4][4] = {};
    for (int kb = 0; kb < cEMB; kb += 16) {
      float4 av = *(const float4*)(ap + kb + lk);
      float4 bv = *(const float4*)(Wp + (size_t)(kb + bk) * cSD + n0 + bn);
      __syncthreads();
      As[lk + 0][lr] = av.x; As[lk + 1][lr] = av.y;
      As[lk + 2][lr] = av.z; As[lk + 3][lr] = av.w;
      *(float4*)&Bs[bk][bn] = bv;
      __syncthreads();
      micro16(As, Bs, r0, c0, acc);
    }
    float4 bpv = *(const float4*)(bp + n0 + c0);
    float bpr[4] = {bpv.x, bpv.y, bpv.z, bpv.w};
    #pragma unroll
    for (int i = 0; i < 4; ++i) {
      int row = rowTile + r0 + i; // packed diag-0 cell
      size_t base = (size_t)row * cSD + n0 + c0;
      #pragma unroll
      for (int e = 0; e < 4; ++e) {
        float v = fmaxf(acc[i][e] + bpr[e], 0.f);
        __hip_bfloat16 h, l;
        split_bf16(v, h, l);
        cfh[base + e] = h;
        cfl[base + e] = l;
      }
    }
  }
}

// ---------------- S2: prep_e || prep_f || uv(diag0) || outer(ln=2) || diag_v ----------------
__global__ __launch_bounds__(256) void k_S2(
    const float* __restrict__ chart_p, const float* __restrict__ G,
    float* __restrict__ e_arr, float* __restrict__ f_arr,
    const __hip_bfloat16* __restrict__ cfh, const __hip_bfloat16* __restrict__ cfl,
    const __hip_bfloat16* __restrict__ WmTh, const __hip_bfloat16* __restrict__ WmTl,
    float* __restrict__ uv, float* __restrict__ Obuf0,
    const float* __restrict__ GsumT, float* __restrict__ chart_v) {
  __shared__ __align__(16) char smraw[40960];
  int bid = blockIdx.x, tid = threadIdx.x;
  if (bid < 2048) {
    // prep_e: e[cell][a][t_lo] = sum_s p_hi[s] G[a][64+s][t]
    float (*As)[68] = (float (*)[68])smraw;
    float (*Bs)[68] = (float (*)[68])(smraw + 4352);
    int rowTile = (bid & 31) * 64;
    int n0 = (bid >> 5) * 64;
    int a = n0 >> 6;
    int lr = tid >> 2, lk = (tid & 3) << 2;
    int bk = tid >> 4, bn = (tid & 15) << 2;
    int r0 = (tid >> 4) << 2, c0 = (tid & 15) << 2;
    float acc[4][4] = {};
    for (int kb = 0; kb < 64; kb += 16) {
      float4 av = *(const float4*)(chart_p + (size_t)(rowTile + lr) * cS + 64 + kb + lk);
      float4 bv = *(const float4*)(G + (size_t)a * 16384 + (size_t)(64 + kb + bk) * 128 + bn);
      __syncthreads();
      As[lk + 0][lr] = av.x; As[lk + 1][lr] = av.y;
      As[lk + 2][lr] = av.z; As[lk + 3][lr] = av.w;
      *(float4*)&Bs[bk][bn] = bv;
      __syncthreads();
      micro16(As, Bs, r0, c0, acc);
    }
    #pragma unroll
    for (int i = 0; i < 4; ++i) {
      float4 o = {acc[i][0], acc[i][1], acc[i][2], acc[i][3]};
      *(float4*)&e_arr[(size_t)(rowTile + r0 + i) * 4096 + n0 + c0] = o;
    }
  } else if (bid < 3072) {
    // prep_f: f[cell][a][s_lo] = sum_t G[a][s][64+t] p_hi[t]
    float* ph = (float*)smraw; // [8][64]
    int fb = bid - 2048;
    int cell0 = (fb & 255) * 8;
    for (int v = tid; v < 512; v += 256) {
      int cc = v >> 6, t = v & 63;
      ph[cc * 64 + t] = chart_p[(size_t)(cell0 + cc) * cS + 64 + t];
    }
    __syncthreads();
    int oo0 = (fb >> 8) * 4;
    for (int oo = oo0; oo < oo0 + 4; ++oo) {
      int out_id = oo * 256 + tid; // a*64 + s
      int a = out_id >> 6, s = out_id & 63;
      const float* gb = G + (size_t)a * 16384 + (size_t)s * 128 + 64;
      float acc[8] = {};
      #pragma unroll 4
      for (int ch = 0; ch < 16; ++ch) {
        float4 g4 = *(const float4*)(gb + ch * 4);
        #pragma unroll
        for (int cc = 0; cc < 8; ++cc) {
          float4 p4 = *(const float4*)&ph[cc * 64 + ch * 4];
          acc[cc] = fmaf(g4.x, p4.x, acc[cc]);
          acc[cc] = fmaf(g4.y, p4.y, acc[cc]);
          acc[cc] = fmaf(g4.z, p4.z, acc[cc]);
          acc[cc] = fmaf(g4.w, p4.w, acc[cc]);
        }
      }
      #pragma unroll
      for (int cc = 0; cc < 8; ++cc)
        f_arr[(size_t)(cell0 + cc) * 4096 + out_id] = acc[cc];
    }
  } else if (bid < 3200) {
    uv_body(smraw, tid, bid - 3072, cfh, cfl, WmTh, WmTl, uv, 0L, 2048);
  } else if (bid < 3200 + 1984) {
    outer_body(smraw, tid, bid - 3200, chart_p, Obuf0, 2, 31, 0, 0, 64, 64);
  } else {
    // diag_v: chart_v for diag 0 (2 cells/block, 1024 blocks = 2048 cells);
    // reads S1's GsumT + chart_p (cross-kernel dependency, legal)
    float* ps = (float*)smraw; // [2][64]
    int vb = bid - (3200 + 1984);
    int rsel = tid >> 7, t = tid & 127;
    size_t base = (size_t)(vb * 2 + rsel) * cS;
    if (t >= 64) ps[rsel * 64 + (t - 64)] = chart_p[base + t];
    __syncthreads();
    float v = 0.f;
    for (int t2 = 0; t2 < 64; ++t2)
      v = fmaf(GsumT[(t2 + 64) * cS + t], ps[rsel * 64 + t2], v);
    chart_v[base + t] = v;
  }
}

// ---------------- X: scores GEMM || outer(ln+1) || combine(ln) ----------------
__global__ __launch_bounds__(256) void k_X(
    const float* __restrict__ Oin, const float* __restrict__ Gq,
    float* __restrict__ scoresP, int gx, int sRows, int sB,
    const float* __restrict__ chart_p, float* __restrict__ Oout,
    int oln, int on, int odlo, int odhi, int oR,
    const float* __restrict__ chart_v, const float* __restrict__ uv,
    const float* __restrict__ bm,
    __hip_bfloat16* __restrict__ cfh, __hip_bfloat16* __restrict__ cfl,
    int ln, int nn) {
  __shared__ __align__(16) char smraw[24576];
  int bid = blockIdx.x;
  int tid = threadIdx.x;
  if (bid < sB) {
    // ======== scores role ========
    float (*As)[128] = (float (*)[128])smraw;            // [32][128]
    float (*Bs)[64] = (float (*)[64])(smraw + 16384);    // [32][64]
    int rt = bid % gx, ks = bid / gx;
    int rowTile = rt * 128;
    int kstart = ks * 256;
    int sm = tid & 127, skq = (tid >> 7) * 16;
    int bq = tid >> 4, bn4 = (tid & 15) * 4;
    int m0 = (tid & 15) << 2, n0 = (tid >> 4) << 2;
    const float* ap = Oin + (size_t)(rowTile + sm) * cKQ + kstart + skq;
    float acc[8][4] = {};
    for (int kb = 0; kb < 256; kb += 32) {
      float4 a0 = *(const float4*)(ap + kb + 0);
      float4 a1 = *(const float4*)(ap + kb + 4);
      float4 a2 = *(const float4*)(ap + kb + 8);
      float4 a3 = *(const float4*)(ap + kb + 12);
      float4 b0 = *(const float4*)(Gq + (size_t)(kstart + kb + bq * 2) * cNT + bn4);
      float4 b1 = *(const float4*)(Gq + (size_t)(kstart + kb + bq * 2 + 1) * cNT + bn4);
      __syncthreads();
      As[skq + 0][sm] = a0.x; As[skq + 1][sm] = a0.y; As[skq + 2][sm] = a0.z; As[skq + 3][sm] = a0.w;
      As[skq + 4][sm] = a1.x; As[skq + 5][sm] = a1.y; As[skq + 6][sm] = a1.z; As[skq + 7][sm] = a1.w;
      As[skq + 8][sm] = a2.x; As[skq + 9][sm] = a2.y; As[skq + 10][sm] = a2.z; As[skq + 11][sm] = a2.w;
      As[skq + 12][sm] = a3.x; As[skq + 13][sm] = a3.y; As[skq + 14][sm] = a3.z; As[skq + 15][sm] = a3.w;
      *(float4*)&Bs[bq * 2][bn4] = b0;
      *(float4*)&Bs[bq * 2 + 1][bn4] = b1;
      __syncthreads();
      #pragma unroll
      for (int k = 0; k < 32; ++k) {
        float4 av0 = *(const float4*)&As[k][m0];
        float4 av1 = *(const float4*)&As[k][m0 + 64];
        float4 bv = *(const float4*)&Bs[k][n0];
        float ar[8] = {av0.x, av0.y, av0.z, av0.w, av1.x, av1.y, av1.z, av1.w};
        float br[4] = {bv.x, bv.y, bv.z, bv.w};
        #pragma unroll
        for (int i = 0; i < 8; ++i)
          #pragma unroll
          for (int j = 0; j < 4; ++j)
            acc[i][j] = fmaf(ar[i], br[j], acc[i][j]);
      }
    }
    #pragma unroll
    for (int i = 0; i < 8; ++i) {
      int row = rowTile + m0 + (i >> 2) * 64 + (i & 3);
      if (row < sRows) {
        float4 o = {acc[i][0], acc[i][1], acc[i][2], acc[i][3]};
        *(float4*)&scoresP[((size_t)ks * CHpad + row) * cNT + n0] = o;
      }
    }
  } else if (bid < sB + oR) {
    outer_body(smraw, tid, bid - sB, chart_p, Oout, oln, on, odlo, odhi, 0, 0);
  } else {
    // ======== combine role (h-split x2) ========
    long* loff = (long*)smraw;                 // 32
    long* roff = loff + 32;                    // 32
    long* lpcS = roff + 32;                    // 32
    long* vpcS = lpcS + 32;                    // 32 (ends 1024 B)
    float* lm = (float*)(smraw + 1024);        // 31
    float* part8 = (float*)(smraw + 1152);     // [32][8]
    int cbid = bid - sB - oR;
    int row = cbid >> 1, hs = cbid & 1;
    int D = ln - 1;
    int b = row / nn, i = row - b * nn;
    if (tid < D) {
      int dd = tid;
      long lc = dBase(dd) + (long)b * (cL - dd) + i;
      int dr = ln - dd - 2;
      long rc = dBase(dr) + (long)b * (cL - dr) + (i + dd + 1);
      loff[dd] = lc * 1024;        // u half
      roff[dd] = rc * 1024 + 512;  // v half
      lpcS[dd] = lc * cS;
      vpcS[dd] = rc * cS;
    }
    __syncthreads();
    int dd8 = tid >> 3, sl = (tid & 7) << 4;
    float prt = 0.f;
    if (dd8 < D) {
      const float* pp = &chart_p[lpcS[dd8] + sl];
      const float* vv = &chart_v[vpcS[dd8] + sl];
      #pragma unroll
      for (int q = 0; q < 4; ++q) {
        float4 p4 = *(const float4*)(pp + q * 4);
        float4 v4 = *(const float4*)(vv + q * 4);
        prt = fmaf(p4.x, v4.x, prt); prt = fmaf(p4.y, v4.y, prt);
        prt = fmaf(p4.z, v4.z, prt); prt = fmaf(p4.w, v4.w, prt);
      }
    }
    part8[dd8 * 8 + (tid & 7)] = prt;
    __syncthreads();
    if (tid < D) {
      float s = 0.f;
      #pragma unroll
      for (int j = 0; j < 8; ++j) s += part8[tid * 8 + j];
      lm[tid] = s;
    }
    __syncthreads();
    float msum = 0.f;
    for (int dd = 0; dd < D; ++dd) msum += lm[dd];
    float inv = 1.f / (msum + cEPS);
    size_t outbase = (size_t)(dBase(ln - 1) + row) * cSD;
    int h = hs * 256 + tid;
    float bmh = bm[h];
    float acc = 0.f;
    for (int dd = 0; dd < D; ++dd) {
      float fe = uv[loff[dd] + h] + uv[roff[dd] + h] + bmh;
      acc = fmaf(lm[dd], fmaxf(fe, 0.f), acc);
    }
    float v = acc * inv;
    __hip_bfloat16 hh, ll;
    split_bf16(v, hh, ll);
    cfh[outbase + h] = hh;
    cfl[outbase + h] = ll;
  }
}

// ---------------- Y: normp || uv(diag ln-1) ----------------
__global__ __launch_bounds__(256) void k_Y(
    const float* __restrict__ scoresP, const float* __restrict__ e_arr,
    const float* __restrict__ f_arr, const float* __restrict__ GsumT,
    float* __restrict__ chart_p, float* __restrict__ chart_v,
    int ln, int nn, int useGemm, int useEF, int Bn,
    const __hip_bfloat16* __restrict__ cfh, const __hip_bfloat16* __restrict__ cfl,
    const __hip_bfloat16* __restrict__ WmTh, const __hip_bfloat16* __restrict__ WmTl,
    float* __restrict__ uv, long uvCellBase, int uvM) {
  __shared__ __align__(16) char smraw[40960];
  int bid = blockIdx.x, tid = threadIdx.x;
  if (bid < Bn) {
    // ======== normp role (4-way lane-parallel) ========
    float* sP = (float*)smraw;             // 128
    float* part = sP + 128;                // [4][64]
    float* ps = part + 256;                // 64
    int row = bid;
    int b = row / nn, i = row - b * nn;
    if (useEF) {
      long c2 = dBase(ln - 2) + (long)b * (nn + 1);
      if (tid < 64)
        sP[tid] = chart_p[(c2 + i + 1) * cS + tid];
      else if (tid < 128)
        sP[tid] = chart_p[(c2 + i) * cS + (tid - 64)];
      __syncthreads();
    }
    int a = tid & 63, g = tid >> 6;
    float val = 0.f;
    if (useGemm) {
      #pragma unroll
      for (int ks = g * 4; ks < g * 4 + 4; ++ks)
        val += scoresP[((size_t)ks * CHpad + row) * cNT + a];
    }
    if (useEF) {
      const float4* e4 = (const float4*)&e_arr[((size_t)(b * cL + i) * 4096) + a * 64];
      const float4* f4 = (const float4*)&f_arr[((size_t)(b * cL + i + ln - 1) * 4096) + a * 64];
      const float4* sP4 = (const float4*)sP;
      #pragma unroll
      for (int q = g * 4; q < g * 4 + 4; ++q) {
        float4 ev = e4[q];
        float4 fv = f4[q];
        float4 rv = sP4[q];
        float4 lv = sP4[16 + q];
        val = fmaf(ev.x, rv.x, val); val = fmaf(ev.y, rv.y, val);
        val = fmaf(ev.z, rv.z, val); val = fmaf(ev.w, rv.w, val);
        val = fmaf(fv.x, lv.x, val); val = fmaf(fv.y, lv.y, val);
        val = fmaf(fv.z, lv.z, val); val = fmaf(fv.w, lv.w, val);
      }
    }
    part[g * 64 + a] = val;
    __syncthreads();
    size_t base = (size_t)(dBase(ln - 1) + row) * cS;
    if (tid < 64) {
      float v = part[a] + part[64 + a] + part[128 + a] + part[192 + a];
      float sum = v;
      #pragma unroll
      for (int off = 1; off < 64; off <<= 1) sum += __shfl_xor(sum, off, 64);
      float p_ = v / (sum + cEPS);
      ps[a] = p_;
      chart_p[base + tid] = p_;
    } else if (tid < 128) {
      chart_p[base + tid] = 0.f;
    }
    __syncthreads();
    if (tid < 128) {
      float v = 0.f;
      for (int t = 0; t < 64; ++t) v = fmaf(GsumT[t * cS + tid], ps[t], v);
      chart_v[base + tid] = v;
    }
  } else {
    uv_body(smraw, tid, bid - Bn, cfh, cfl, WmTh, WmTl, uv, uvCellBase, uvM);
  }
}

// ---------------- root ----------------
__global__ void k_root(const float* __restrict__ chart_p,
                       const __hip_bfloat16* __restrict__ cfh,
                       const __hip_bfloat16* __restrict__ cfl,
                       const float* __restrict__ starts,
                       float* __restrict__ out) {
  __shared__ float red[2];
  int b = blockIdx.x, tid = threadIdx.x; // 128
  long cell = dBase(cL - 1) + b;
  float v = chart_p[cell * cS + tid] * starts[tid];
  #pragma unroll
  for (int off = 1; off < 64; off <<= 1) v += __shfl_xor(v, off, 64);
  if ((tid & 63) == 0) red[tid >> 6] = v;
  __syncthreads();
  float score = red[0] + red[1];
  size_t fbase = (size_t)cell * cSD;
  for (int h = tid; h < cSD; h += 128) {
    float f = __bfloat162float(cfh[fbase + h]) + __bfloat162float(cfl[fbase + h]);
    out[(size_t)b * cSD + h] = f * score;
  }
}

extern "C" void kernel_launch(void* const* d_in, const int* in_sizes, int n_in,
                              void* d_out, int out_size, void* d_ws, size_t ws_size,
                              hipStream_t stream) {
  const int* word = (const int*)d_in[0];
  const float* WE = (const float*)d_in[1];
  const float* preterm = (const float*)d_in[2];
  const float* G = (const float*)d_in[3];
  const float* starts = (const float*)d_in[4];
  const float* Wp = (const float*)d_in[5];
  const float* bp = (const float*)d_in[6];
  const float* Wm = (const float*)d_in[7];
  const float* bm = (const float*)d_in[8];
  float* out = (float*)d_out;
  float* ws = (float*)d_ws;

  size_t off = 0;
  float* chart_p = ws + off; off += (size_t)TRIC * cS;           // 17.3 MB
  float* chart_v = ws + off; off += (size_t)TRIC * cS;           // 17.3 MB
  __hip_bfloat16* cfh = (__hip_bfloat16*)(ws + off); off += (size_t)TRIC * cSD / 2; // 34.6 MB
  __hip_bfloat16* cfl = (__hip_bfloat16*)(ws + off); off += (size_t)TRIC * cSD / 2; // 34.6 MB
  float* Gll = ws + off; off += (size_t)cKQ * cNT;               // 1 MB
  float* Ghh = ws + off; off += (size_t)cKQ * cNT;               // 1 MB
  float* GsumT = ws + off; off += cS * cS;
  float* e_arr = ws + off; off += (size_t)2048 * 4096;           // 33.5 MB
  float* f_arr = ws + off; off += (size_t)2048 * 4096;           // 33.5 MB
  __hip_bfloat16* WmTh = (__hip_bfloat16*)(ws + off); off += (size_t)cSD * 1024 / 2;
  __hip_bfloat16* WmTl = (__hip_bfloat16*)(ws + off); off += (size_t)cSD * 1024 / 2;
  float* uv = ws + off; off += (size_t)TRIC * 1024;              // 138.4 MB packed
  float* Obuf0 = ws + off; off += (size_t)CHpad * cKQ;           // 32.5 MB
  float* Obuf1 = ws + off; off += (size_t)CHpad * cKQ;           // 32.5 MB
  float* scoresP = ws + off; off += (size_t)CHpad * KS * cNT;    // 8.1 MB
  // total ~386.7 MB <= 409.6 MB (measured via harness fill WRITE_SIZE)

  auto hdB = [](int d) { return (long)cB * ((long)d * cL - (long)d * (d - 1) / 2); };

  // S1: prep_g(64) || prep_wmt(2048) || diag_p(1024, 2 cells/blk) || feat0(256)
  k_S1<<<64 + 2048 + 1024 + 256, 256, 0, stream>>>(
      G, Gll, Ghh, GsumT, Wm, WmTh, WmTl, word, preterm, chart_p,
      WE, Wp, bp, cfh, cfl);
  // S2: prep_e(2048) || prep_f(1024) || uv(diag0,128) || outer(ln=2,1984)
  //     || diag_v(1024, 2 cells/blk = all 2048 diag-0 cells)
  k_S2<<<2048 + 1024 + 128 + 1984 + 1024, 256, 0, stream>>>(
      chart_p, G, e_arr, f_arr, cfh, cfl, WmTh, WmTl, uv, Obuf0, GsumT, chart_v);

  for (int ln = 2; ln <= cL; ++ln) {
    int n = cL - ln + 1, Bn = cB * n;
    int useGemm = (ln == 2 || ln >= 4) ? 1 : 0;
    int useEF = (ln >= 3) ? 1 : 0;
    int gx = useGemm ? (Bn + 127) / 128 : 0;
    int sB = gx * KS;
    int oR = (ln >= 3 && ln <= cL - 1) ? cB * (cL - ln) : 0; // rows of diag ln+1
    const float* Oin = (ln & 1) ? Obuf1 : Obuf0;
    float* Oout = ((ln + 1) & 1) ? Obuf1 : Obuf0;
    // X(ln): scores(ln) || outer(ln+1) || combine(ln)
    k_X<<<sB + oR + 2 * Bn, 256, 0, stream>>>(
        Oin, (ln == 2) ? Ghh : Gll, scoresP, gx, Bn, sB,
        chart_p, Oout, ln + 1, cL - ln, 1, ln - 2, oR,
        chart_v, uv, bm, cfh, cfl, ln, n);
    // Y(ln): normp(ln) || uv(diag ln-1)
    int uB = (ln < cL) ? ((Bn + 127) / 128) * 8 : 0;
    k_Y<<<Bn + uB, 256, 0, stream>>>(
        scoresP, e_arr, f_arr, GsumT, chart_p, chart_v,
        ln, n, useGemm, useEF, Bn,
        cfh, cfl, WmTh, WmTl, uv, hdB(ln - 1), Bn);
  }

  k_root<<<cB, 128, 0, stream>>>(chart_p, cfh, cfl, starts, out);
}

// Round 8
// 1894.947 us; speedup vs baseline: 1.0276x; 1.0276x over previous
//
#include <hip/hip_runtime.h>
#include <hip/hip_bf16.h>

// CYK forward. p-chain fp32; f-chain GEMM bf16x3 MFMA.
// Round 15: revert phase roles to round-4 split (X = scores||uv||outer all
// 40KB-LDS heavy roles; Y = normp||combine both light) — round 14's
// Y = normp||uv put uv's static 40KB smraw in normp's kernel, collapsing
// the e/f-streaming normp role to 4 blocks/CU (OccupancyPercent 20%) and
// regressing 74us. Y now uses 2.3KB LDS. Kept from rounds 12-14: S1/S2
// merged setup (2 launches), combine one-shot masses + h-split x2, KS=16,
// diag_v race/coverage fixes.

typedef __attribute__((ext_vector_type(8))) short short8;
typedef __attribute__((ext_vector_type(4))) float f32x4;

constexpr int cB = 64, cL = 32, cNT = 64, cS = 128, cV = 50000;
constexpr int cEMB = 512, cSD = 512, cKQ = 4096; // quadrant k
constexpr int DMAX = 31, KS = 16;                // k-slice = 256
constexpr int CHpad = 1984;
constexpr float cEPS = 1e-9f;
constexpr long TRIC = (long)cB * (cL * (cL + 1) / 2); // 33792 packed cells

__device__ __forceinline__ long dBase(int d) {
  return (long)cB * ((long)d * cL - ((long)d * (d - 1)) / 2);
}

__device__ __forceinline__ void split_bf16(float x, __hip_bfloat16& h, __hip_bfloat16& l) {
  h = __float2bfloat16(x);
  l = __float2bfloat16(x - __bfloat162float(h));
}

// ---------------- fp32 GEMM micro ----------------
__device__ __forceinline__ void micro16(const float (*As)[68], const float (*Bs)[68],
                                        int r0, int c0, float acc[4][4]) {
  #pragma unroll
  for (int k = 0; k < 16; ++k) {
    float4 a4 = *(const float4*)&As[k][r0];
    float4 b4 = *(const float4*)&Bs[k][c0];
    float ar[4] = {a4.x, a4.y, a4.z, a4.w};
    float br[4] = {b4.x, b4.y, b4.z, b4.w};
    #pragma unroll
    for (int i = 0; i < 4; ++i)
      #pragma unroll
      for (int j = 0; j < 4; ++j)
        acc[i][j] = fmaf(ar[i], br[j], acc[i][j]);
  }
}

// ---------------- uv GEMM body (bf16x3 MFMA, 128x128 tile, K=512) ----------------
__device__ __forceinline__ void uv_body(
    char* smraw, int tid, int ubid,
    const __hip_bfloat16* __restrict__ cfh, const __hip_bfloat16* __restrict__ cfl,
    const __hip_bfloat16* __restrict__ WmTh, const __hip_bfloat16* __restrict__ WmTl,
    float* __restrict__ uv, long cellBase, int M) {
  short* Ash = (short*)smraw;              // [2*128][40]
  short* Bsh = (short*)(smraw + 20480);    // [2*128][40]
  int colTile = (ubid & 7) << 7;
  int rowTile = (ubid >> 3) << 7;
  int m0 = tid >> 2, kq8 = (tid & 3) * 8;

  long offA[2];
  #pragma unroll
  for (int h = 0; h < 2; ++h) {
    int row = rowTile + m0 + h * 64;
    if (row >= M) row = M - 1;
    offA[h] = (cellBase + row) * cSD;
  }
  long offB0 = (long)(colTile + m0) * 512;
  long offB1 = (long)(colTile + m0 + 64) * 512;

  f32x4 acc[4][4];
  f32x4 zero = {0.f, 0.f, 0.f, 0.f};
  #pragma unroll
  for (int a_ = 0; a_ < 4; ++a_)
    #pragma unroll
    for (int b_ = 0; b_ < 4; ++b_) acc[a_][b_] = zero;

  int lane = tid & 63, wid = tid >> 6;
  int wm = wid >> 1, wn = wid & 1;
  int fr = lane & 15, fq = lane >> 4;

  int4 pA0h = *(const int4*)(const void*)(cfh + offA[0] + kq8);
  int4 pA1h = *(const int4*)(const void*)(cfh + offA[1] + kq8);
  int4 pA0l = *(const int4*)(const void*)(cfl + offA[0] + kq8);
  int4 pA1l = *(const int4*)(const void*)(cfl + offA[1] + kq8);
  int4 pB0h = *(const int4*)(const void*)(WmTh + offB0 + kq8);
  int4 pB1h = *(const int4*)(const void*)(WmTh + offB1 + kq8);
  int4 pB0l = *(const int4*)(const void*)(WmTl + offB0 + kq8);
  int4 pB1l = *(const int4*)(const void*)(WmTl + offB1 + kq8);

  for (int kb = 0; kb < 512; kb += 32) {
    __syncthreads();
    *(int4*)&Ash[(0 * 128 + m0) * 40 + kq8] = pA0h;
    *(int4*)&Ash[(0 * 128 + m0 + 64) * 40 + kq8] = pA1h;
    *(int4*)&Ash[(1 * 128 + m0) * 40 + kq8] = pA0l;
    *(int4*)&Ash[(1 * 128 + m0 + 64) * 40 + kq8] = pA1l;
    *(int4*)&Bsh[(0 * 128 + m0) * 40 + kq8] = pB0h;
    *(int4*)&Bsh[(0 * 128 + m0 + 64) * 40 + kq8] = pB1h;
    *(int4*)&Bsh[(1 * 128 + m0) * 40 + kq8] = pB0l;
    *(int4*)&Bsh[(1 * 128 + m0 + 64) * 40 + kq8] = pB1l;
    __syncthreads();
    int kn = kb + 32;
    if (kn < 512) {
      pA0h = *(const int4*)(const void*)(cfh + offA[0] + kn + kq8);
      pA1h = *(const int4*)(const void*)(cfh + offA[1] + kn + kq8);
      pA0l = *(const int4*)(const void*)(cfl + offA[0] + kn + kq8);
      pA1l = *(const int4*)(const void*)(cfl + offA[1] + kn + kq8);
      pB0h = *(const int4*)(const void*)(WmTh + offB0 + kn + kq8);
      pB1h = *(const int4*)(const void*)(WmTh + offB1 + kn + kq8);
      pB0l = *(const int4*)(const void*)(WmTl + offB0 + kn + kq8);
      pB1l = *(const int4*)(const void*)(WmTl + offB1 + kn + kq8);
    }
    short8 af[2][4], bf[2][4];
    #pragma unroll
    for (int pl = 0; pl < 2; ++pl)
      #pragma unroll
      for (int mf = 0; mf < 4; ++mf)
        af[pl][mf] = *(const short8*)&Ash[(pl * 128 + wm * 64 + mf * 16 + fr) * 40 + fq * 8];
    #pragma unroll
    for (int pl = 0; pl < 2; ++pl)
      #pragma unroll
      for (int nf = 0; nf < 4; ++nf)
        bf[pl][nf] = *(const short8*)&Bsh[(pl * 128 + wn * 64 + nf * 16 + fr) * 40 + fq * 8];
    #pragma unroll
    for (int mf = 0; mf < 4; ++mf)
      #pragma unroll
      for (int nf = 0; nf < 4; ++nf) {
        acc[mf][nf] = __builtin_amdgcn_mfma_f32_16x16x32_bf16(af[0][mf], bf[0][nf], acc[mf][nf], 0, 0, 0);
        acc[mf][nf] = __builtin_amdgcn_mfma_f32_16x16x32_bf16(af[0][mf], bf[1][nf], acc[mf][nf], 0, 0, 0);
        acc[mf][nf] = __builtin_amdgcn_mfma_f32_16x16x32_bf16(af[1][mf], bf[0][nf], acc[mf][nf], 0, 0, 0);
      }
  }
  #pragma unroll
  for (int mf = 0; mf < 4; ++mf)
    #pragma unroll
    for (int r = 0; r < 4; ++r) {
      int row = rowTile + wm * 64 + mf * 16 + fq * 4 + r;
      if (row >= M) continue;
      float* op = uv + (cellBase + row) * 1024 + colTile + wn * 64;
      #pragma unroll
      for (int nf = 0; nf < 4; ++nf)
        op[nf * 16 + fr] = acc[mf][nf][r];
    }
}

// ---------------- outer-product body ----------------
__device__ __forceinline__ void outer_body(
    char* smraw, int tid, int lr, const float* __restrict__ chart_p,
    float* __restrict__ Oout, int oln, int on, int odlo, int odhi,
    int osoff, int otoff) {
  float* lp = (float*)smraw;                  // [DMAX][64]
  float* rp = (float*)(smraw + DMAX * 64 * 4);
  int b = lr / on, i = lr - b * on;
  if (tid < 128) {
    int lane = tid & 63;
    for (int dd = odlo + (tid >> 6); dd <= odhi; dd += 2) {
      long lc = dBase(dd) + (long)b * (cL - dd) + i;
      lp[(dd - odlo) * 64 + lane] = chart_p[lc * cS + osoff + lane];
    }
  } else {
    int t2 = tid - 128;
    int lane = t2 & 63;
    for (int dd = odlo + (t2 >> 6); dd <= odhi; dd += 2) {
      int dr = oln - dd - 2;
      long rc = dBase(dr) + (long)b * (cL - dr) + (i + dd + 1);
      rp[(dd - odlo) * 64 + lane] = chart_p[rc * cS + otoff + lane];
    }
  }
  __syncthreads();
  float acc[16];
  #pragma unroll
  for (int j = 0; j < 16; ++j) acc[j] = 0.f;
  int s = tid >> 2, t0 = (tid & 3) << 4;
  int dcount = odhi - odlo + 1;
  for (int dd = 0; dd < dcount; ++dd) {
    float lps = lp[dd * 64 + s];
    #pragma unroll
    for (int qq = 0; qq < 4; ++qq) {
      float4 r4 = *(const float4*)&rp[dd * 64 + t0 + qq * 4];
      acc[qq * 4 + 0] = fmaf(lps, r4.x, acc[qq * 4 + 0]);
      acc[qq * 4 + 1] = fmaf(lps, r4.y, acc[qq * 4 + 1]);
      acc[qq * 4 + 2] = fmaf(lps, r4.z, acc[qq * 4 + 2]);
      acc[qq * 4 + 3] = fmaf(lps, r4.w, acc[qq * 4 + 3]);
    }
  }
  float* op = Oout + (size_t)lr * cKQ + (size_t)tid * 16; // p = s*64+t
  #pragma unroll
  for (int j = 0; j < 4; ++j) {
    float4 o = {acc[j * 4 + 0], acc[j * 4 + 1], acc[j * 4 + 2], acc[j * 4 + 3]};
    *(float4*)&op[j * 4] = o;
  }
}

// ---------------- S1: prep_g || prep_wmt || diag_p || feat0 ----------------
// diag_p writes chart_p ONLY (diag-0 chart_v computed in S2's diag_v role;
// GsumT is written by prep_g in THIS kernel — no intra-kernel ordering).
__global__ __launch_bounds__(256) void k_S1(
    const float* __restrict__ G, float* __restrict__ Gll, float* __restrict__ Ghh,
    float* __restrict__ GsumT, const float* __restrict__ Wm,
    __hip_bfloat16* __restrict__ WmTh, __hip_bfloat16* __restrict__ WmTl,
    const int* __restrict__ word, const float* __restrict__ preterm,
    float* __restrict__ chart_p,
    const float* __restrict__ WE, const float* __restrict__ Wp,
    const float* __restrict__ bp,
    __hip_bfloat16* __restrict__ cfh, __hip_bfloat16* __restrict__ cfl) {
  __shared__ __align__(16) char smraw[8704];
  int bid = blockIdx.x, tid = threadIdx.x;
  if (bid < 64) {
    // prep_g
    int idx = bid * 256 + tid; // s*128+t
    int s = idx >> 7, t = idx & 127;
    bool lo = (s < 64) && (t < 64);
    bool hi = (s >= 64) && (t >= 64);
    int pl = s * 64 + t;
    int ph = (s - 64) * 64 + (t - 64);
    float accum = 0.f;
    for (int a = 0; a < cNT; ++a) {
      float g = G[(size_t)a * 16384 + idx];
      accum += g;
      if (lo) Gll[(size_t)pl * cNT + a] = g;
      if (hi) Ghh[(size_t)ph * cNT + a] = g;
    }
    GsumT[t * cS + s] = accum;
  } else if (bid < 64 + 2048) {
    // prep_wmt: layout [nn<1024][k<512]
    int idx = (bid - 64) * 256 + tid; // nn*512 + k
    int k = idx & 511, nn = idx >> 9;
    int krow = k + ((nn >= 512) ? 512 : 0);
    float v = Wm[(size_t)krow * cSD + (nn & 511)];
    __hip_bfloat16 h, l;
    split_bf16(v, h, l);
    WmTh[idx] = h;
    WmTl[idx] = l;
  } else if (bid < 64 + 2048 + 1024) {
    // diag_p: 2 cells per block; chart_p only
    int dbid = bid - (64 + 2048);
    int rsel = tid >> 7, t = tid & 127;
    int r2 = dbid * 2 + rsel;
    int w = word[r2];
    float val = (t >= 64) ? preterm[(size_t)(t - 64) * cV + w] : 0.f;
    float sum = val;
    #pragma unroll
    for (int off = 1; off < 64; off <<= 1) sum += __shfl_xor(sum, off, 64);
    float p_ = (t >= 64) ? val / (sum + cEPS) : 0.f;
    chart_p[(size_t)r2 * cS + t] = p_;
  } else {
    // feat0
    float (*As)[68] = (float (*)[68])smraw;
    float (*Bs)[68] = (float (*)[68])(smraw + 4352);
    int fb = bid - (64 + 2048 + 1024);
    int rowTile = (fb >> 3) * 64;
    int n0 = (fb & 7) * 64;
    int lr = tid >> 2, lk = (tid & 3) << 2;
    int bk = tid >> 4, bn = (tid & 15) << 2;
    int r0 = (tid >> 4) << 2, c0 = (tid & 15) << 2;
    const float* ap = WE + (size_t)word[rowTile + lr] * cEMB;
    float acc[4][4] = {};
    for (int kb = 0; kb < cEMB; kb += 16) {
      float4 av = *(const float4*)(ap + kb + lk);
      float4 bv = *(const float4*)(Wp + (size_t)(kb + bk) * cSD + n0 + bn);
      __syncthreads();
      As[lk + 0][lr] = av.x; As[lk + 1][lr] = av.y;
      As[lk + 2][lr] = av.z; As[lk + 3][lr] = av.w;
      *(float4*)&Bs[bk][bn] = bv;
      __syncthreads();
      micro16(As, Bs, r0, c0, acc);
    }
    float4 bpv = *(const float4*)(bp + n0 + c0);
    float bpr[4] = {bpv.x, bpv.y, bpv.z, bpv.w};
    #pragma unroll
    for (int i = 0; i < 4; ++i) {
      int row = rowTile + r0 + i; // packed diag-0 cell
      size_t base = (size_t)row * cSD + n0 + c0;
      #pragma unroll
      for (int e = 0; e < 4; ++e) {
        float v = fmaxf(acc[i][e] + bpr[e], 0.f);
        __hip_bfloat16 h, l;
        split_bf16(v, h, l);
        cfh[base + e] = h;
        cfl[base + e] = l;
      }
    }
  }
}

// ---------------- S2: prep_e || prep_f || uv(diag0) || outer(ln=2) || diag_v ----------------
__global__ __launch_bounds__(256) void k_S2(
    const float* __restrict__ chart_p, const float* __restrict__ G,
    float* __restrict__ e_arr, float* __restrict__ f_arr,
    const __hip_bfloat16* __restrict__ cfh, const __hip_bfloat16* __restrict__ cfl,
    const __hip_bfloat16* __restrict__ WmTh, const __hip_bfloat16* __restrict__ WmTl,
    float* __restrict__ uv, float* __restrict__ Obuf0,
    const float* __restrict__ GsumT, float* __restrict__ chart_v) {
  __shared__ __align__(16) char smraw[40960];
  int bid = blockIdx.x, tid = threadIdx.x;
  if (bid < 2048) {
    // prep_e: e[cell][a][t_lo] = sum_s p_hi[s] G[a][64+s][t]
    float (*As)[68] = (float (*)[68])smraw;
    float (*Bs)[68] = (float (*)[68])(smraw + 4352);
    int rowTile = (bid & 31) * 64;
    int n0 = (bid >> 5) * 64;
    int a = n0 >> 6;
    int lr = tid >> 2, lk = (tid & 3) << 2;
    int bk = tid >> 4, bn = (tid & 15) << 2;
    int r0 = (tid >> 4) << 2, c0 = (tid & 15) << 2;
    float acc[4][4] = {};
    for (int kb = 0; kb < 64; kb += 16) {
      float4 av = *(const float4*)(chart_p + (size_t)(rowTile + lr) * cS + 64 + kb + lk);
      float4 bv = *(const float4*)(G + (size_t)a * 16384 + (size_t)(64 + kb + bk) * 128 + bn);
      __syncthreads();
      As[lk + 0][lr] = av.x; As[lk + 1][lr] = av.y;
      As[lk + 2][lr] = av.z; As[lk + 3][lr] = av.w;
      *(float4*)&Bs[bk][bn] = bv;
      __syncthreads();
      micro16(As, Bs, r0, c0, acc);
    }
    #pragma unroll
    for (int i = 0; i < 4; ++i) {
      float4 o = {acc[i][0], acc[i][1], acc[i][2], acc[i][3]};
      *(float4*)&e_arr[(size_t)(rowTile + r0 + i) * 4096 + n0 + c0] = o;
    }
  } else if (bid < 3072) {
    // prep_f: f[cell][a][s_lo] = sum_t G[a][s][64+t] p_hi[t]
    float* ph = (float*)smraw; // [8][64]
    int fb = bid - 2048;
    int cell0 = (fb & 255) * 8;
    for (int v = tid; v < 512; v += 256) {
      int cc = v >> 6, t = v & 63;
      ph[cc * 64 + t] = chart_p[(size_t)(cell0 + cc) * cS + 64 + t];
    }
    __syncthreads();
    int oo0 = (fb >> 8) * 4;
    for (int oo = oo0; oo < oo0 + 4; ++oo) {
      int out_id = oo * 256 + tid; // a*64 + s
      int a = out_id >> 6, s = out_id & 63;
      const float* gb = G + (size_t)a * 16384 + (size_t)s * 128 + 64;
      float acc[8] = {};
      #pragma unroll 4
      for (int ch = 0; ch < 16; ++ch) {
        float4 g4 = *(const float4*)(gb + ch * 4);
        #pragma unroll
        for (int cc = 0; cc < 8; ++cc) {
          float4 p4 = *(const float4*)&ph[cc * 64 + ch * 4];
          acc[cc] = fmaf(g4.x, p4.x, acc[cc]);
          acc[cc] = fmaf(g4.y, p4.y, acc[cc]);
          acc[cc] = fmaf(g4.z, p4.z, acc[cc]);
          acc[cc] = fmaf(g4.w, p4.w, acc[cc]);
        }
      }
      #pragma unroll
      for (int cc = 0; cc < 8; ++cc)
        f_arr[(size_t)(cell0 + cc) * 4096 + out_id] = acc[cc];
    }
  } else if (bid < 3200) {
    uv_body(smraw, tid, bid - 3072, cfh, cfl, WmTh, WmTl, uv, 0L, 2048);
  } else if (bid < 3200 + 1984) {
    outer_body(smraw, tid, bid - 3200, chart_p, Obuf0, 2, 31, 0, 0, 64, 64);
  } else {
    // diag_v: chart_v for diag 0 (2 cells/block, 1024 blocks = 2048 cells);
    // reads S1's GsumT + chart_p (cross-kernel dependency, legal)
    float* ps = (float*)smraw; // [2][64]
    int vb = bid - (3200 + 1984);
    int rsel = tid >> 7, t = tid & 127;
    size_t base = (size_t)(vb * 2 + rsel) * cS;
    if (t >= 64) ps[rsel * 64 + (t - 64)] = chart_p[base + t];
    __syncthreads();
    float v = 0.f;
    for (int t2 = 0; t2 < 64; ++t2)
      v = fmaf(GsumT[(t2 + 64) * cS + t], ps[rsel * 64 + t2], v);
    chart_v[base + t] = v;
  }
}

// ---------------- X: scores GEMM || uv(diag ln-2) || outer(ln+1) ----------------
// All 40KB-LDS / heavyweight roles together; legality: all depend only on
// Y(ln-1) outputs. Oin/Oout are distinct buffers (parity double-buffer).
__global__ __launch_bounds__(256) void k_X(
    const float* __restrict__ Oin, const float* __restrict__ Gq,
    float* __restrict__ scoresP, int gx, int sRows, int sB,
    const __hip_bfloat16* __restrict__ cfh, const __hip_bfloat16* __restrict__ cfl,
    const __hip_bfloat16* __restrict__ WmTh, const __hip_bfloat16* __restrict__ WmTl,
    float* __restrict__ uv, long uvCellBase, int uvM, int uB,
    const float* __restrict__ chart_p, float* __restrict__ Oout,
    int oln, int on, int odlo, int odhi) {
  __shared__ __align__(16) char smraw[40960];
  int bid = blockIdx.x;
  int tid = threadIdx.x;
  if (bid < sB) {
    // ======== scores role ========
    float (*As)[128] = (float (*)[128])smraw;            // [32][128]
    float (*Bs)[64] = (float (*)[64])(smraw + 16384);    // [32][64]
    int rt = bid % gx, ks = bid / gx;
    int rowTile = rt * 128;
    int kstart = ks * 256;
    int sm = tid & 127, skq = (tid >> 7) * 16;
    int bq = tid >> 4, bn4 = (tid & 15) * 4;
    int m0 = (tid & 15) << 2, n0 = (tid >> 4) << 2;
    const float* ap = Oin + (size_t)(rowTile + sm) * cKQ + kstart + skq;
    float acc[8][4] = {};
    for (int kb = 0; kb < 256; kb += 32) {
      float4 a0 = *(const float4*)(ap + kb + 0);
      float4 a1 = *(const float4*)(ap + kb + 4);
      float4 a2 = *(const float4*)(ap + kb + 8);
      float4 a3 = *(const float4*)(ap + kb + 12);
      float4 b0 = *(const float4*)(Gq + (size_t)(kstart + kb + bq * 2) * cNT + bn4);
      float4 b1 = *(const float4*)(Gq + (size_t)(kstart + kb + bq * 2 + 1) * cNT + bn4);
      __syncthreads();
      As[skq + 0][sm] = a0.x; As[skq + 1][sm] = a0.y; As[skq + 2][sm] = a0.z; As[skq + 3][sm] = a0.w;
      As[skq + 4][sm] = a1.x; As[skq + 5][sm] = a1.y; As[skq + 6][sm] = a1.z; As[skq + 7][sm] = a1.w;
      As[skq + 8][sm] = a2.x; As[skq + 9][sm] = a2.y; As[skq + 10][sm] = a2.z; As[skq + 11][sm] = a2.w;
      As[skq + 12][sm] = a3.x; As[skq + 13][sm] = a3.y; As[skq + 14][sm] = a3.z; As[skq + 15][sm] = a3.w;
      *(float4*)&Bs[bq * 2][bn4] = b0;
      *(float4*)&Bs[bq * 2 + 1][bn4] = b1;
      __syncthreads();
      #pragma unroll
      for (int k = 0; k < 32; ++k) {
        float4 av0 = *(const float4*)&As[k][m0];
        float4 av1 = *(const float4*)&As[k][m0 + 64];
        float4 bv = *(const float4*)&Bs[k][n0];
        float ar[8] = {av0.x, av0.y, av0.z, av0.w, av1.x, av1.y, av1.z, av1.w};
        float br[4] = {bv.x, bv.y, bv.z, bv.w};
        #pragma unroll
        for (int i = 0; i < 8; ++i)
          #pragma unroll
          for (int j = 0; j < 4; ++j)
            acc[i][j] = fmaf(ar[i], br[j], acc[i][j]);
      }
    }
    #pragma unroll
    for (int i = 0; i < 8; ++i) {
      int row = rowTile + m0 + (i >> 2) * 64 + (i & 3);
      if (row < sRows) {
        float4 o = {acc[i][0], acc[i][1], acc[i][2], acc[i][3]};
        *(float4*)&scoresP[((size_t)ks * CHpad + row) * cNT + n0] = o;
      }
    }
  } else if (bid < sB + uB) {
    uv_body(smraw, tid, bid - sB, cfh, cfl, WmTh, WmTl, uv, uvCellBase, uvM);
  } else {
    outer_body(smraw, tid, bid - sB - uB, chart_p, Oout, oln, on, odlo, odhi, 0, 0);
  }
}

// ---------------- Y: normp || combine (both light; 2.3KB LDS) ----------------
__global__ __launch_bounds__(256) void k_Y(
    const float* __restrict__ scoresP, const float* __restrict__ e_arr,
    const float* __restrict__ f_arr, const float* __restrict__ GsumT,
    float* __restrict__ chart_p, float* __restrict__ chart_v,
    const float* __restrict__ uv, const float* __restrict__ bm,
    __hip_bfloat16* __restrict__ cfh, __hip_bfloat16* __restrict__ cfl,
    int ln, int nn, int useGemm, int useEF, int Bn) {
  __shared__ __align__(16) char smraw[2304];
  int bid = blockIdx.x, tid = threadIdx.x;
  if (bid < Bn) {
    // ======== normp role (4-way lane-parallel) ========
    float* sP = (float*)smraw;             // 128 floats
    float* part = sP + 128;                // [4][64]
    float* ps = part + 256;                // 64
    int row = bid;
    int b = row / nn, i = row - b * nn;
    if (useEF) {
      long c2 = dBase(ln - 2) + (long)b * (nn + 1); // width at diag ln-2 is nn+1
      if (tid < 64)
        sP[tid] = chart_p[(c2 + i + 1) * cS + tid];
      else if (tid < 128)
        sP[tid] = chart_p[(c2 + i) * cS + (tid - 64)];
      __syncthreads();
    }
    int a = tid & 63, g = tid >> 6;
    float val = 0.f;
    if (useGemm) {
      #pragma unroll
      for (int ks = g * 4; ks < g * 4 + 4; ++ks)
        val += scoresP[((size_t)ks * CHpad + row) * cNT + a];
    }
    if (useEF) {
      const float4* e4 = (const float4*)&e_arr[((size_t)(b * cL + i) * 4096) + a * 64];
      const float4* f4 = (const float4*)&f_arr[((size_t)(b * cL + i + ln - 1) * 4096) + a * 64];
      const float4* sP4 = (const float4*)sP;
      #pragma unroll
      for (int q = g * 4; q < g * 4 + 4; ++q) {
        float4 ev = e4[q];
        float4 fv = f4[q];
        float4 rv = sP4[q];
        float4 lv = sP4[16 + q];
        val = fmaf(ev.x, rv.x, val); val = fmaf(ev.y, rv.y, val);
        val = fmaf(ev.z, rv.z, val); val = fmaf(ev.w, rv.w, val);
        val = fmaf(fv.x, lv.x, val); val = fmaf(fv.y, lv.y, val);
        val = fmaf(fv.z, lv.z, val); val = fmaf(fv.w, lv.w, val);
      }
    }
    part[g * 64 + a] = val;
    __syncthreads();
    size_t base = (size_t)(dBase(ln - 1) + row) * cS;
    if (tid < 64) {
      float v = part[a] + part[64 + a] + part[128 + a] + part[192 + a];
      float sum = v;
      #pragma unroll
      for (int off = 1; off < 64; off <<= 1) sum += __shfl_xor(sum, off, 64);
      float p_ = v / (sum + cEPS);
      ps[a] = p_;
      chart_p[base + tid] = p_;
    } else if (tid < 128) {
      chart_p[base + tid] = 0.f;
    }
    __syncthreads();
    if (tid < 128) {
      float v = 0.f;
      for (int t = 0; t < 64; ++t) v = fmaf(GsumT[t * cS + tid], ps[t], v);
      chart_v[base + tid] = v;
    }
  } else {
    // ======== combine role (h-split x2; one-shot masses) ========
    long* loff = (long*)smraw;                 // 32 longs
    long* roff = loff + 32;
    long* lpcS = roff + 32;
    long* vpcS = lpcS + 32;                    // ends at 1024 B
    float* lm = (float*)(smraw + 1024);        // 31 floats (pad to 1152)
    float* part8 = (float*)(smraw + 1152);     // [32][8] floats -> ends 2176
    int cbid = bid - Bn;
    int row = cbid >> 1, hs = cbid & 1;
    int D = ln - 1;
    int b = row / nn, i = row - b * nn;
    if (tid < D) {
      int dd = tid;
      long lc = dBase(dd) + (long)b * (cL - dd) + i;
      int dr = ln - dd - 2;
      long rc = dBase(dr) + (long)b * (cL - dr) + (i + dd + 1);
      loff[dd] = lc * 1024;        // u half
      roff[dd] = rc * 1024 + 512;  // v half
      lpcS[dd] = lc * cS;
      vpcS[dd] = rc * cS;
    }
    __syncthreads();
    int dd8 = tid >> 3, sl = (tid & 7) << 4;
    float prt = 0.f;
    if (dd8 < D) {
      const float* pp = &chart_p[lpcS[dd8] + sl];
      const float* vv = &chart_v[vpcS[dd8] + sl];
      #pragma unroll
      for (int q = 0; q < 4; ++q) {
        float4 p4 = *(const float4*)(pp + q * 4);
        float4 v4 = *(const float4*)(vv + q * 4);
        prt = fmaf(p4.x, v4.x, prt); prt = fmaf(p4.y, v4.y, prt);
        prt = fmaf(p4.z, v4.z, prt); prt = fmaf(p4.w, v4.w, prt);
      }
    }
    part8[dd8 * 8 + (tid & 7)] = prt;
    __syncthreads();
    if (tid < D) {
      float s = 0.f;
      #pragma unroll
      for (int j = 0; j < 8; ++j) s += part8[tid * 8 + j];
      lm[tid] = s;
    }
    __syncthreads();
    float msum = 0.f;
    for (int dd = 0; dd < D; ++dd) msum += lm[dd];
    float inv = 1.f / (msum + cEPS);
    size_t outbase = (size_t)(dBase(ln - 1) + row) * cSD;
    int h = hs * 256 + tid;
    float bmh = bm[h];
    float acc = 0.f;
    for (int dd = 0; dd < D; ++dd) {
      float fe = uv[loff[dd] + h] + uv[roff[dd] + h] + bmh;
      acc = fmaf(lm[dd], fmaxf(fe, 0.f), acc);
    }
    float v = acc * inv;
    __hip_bfloat16 hh, ll;
    split_bf16(v, hh, ll);
    cfh[outbase + h] = hh;
    cfl[outbase + h] = ll;
  }
}

// ---------------- root ----------------
__global__ void k_root(const float* __restrict__ chart_p,
                       const __hip_bfloat16* __restrict__ cfh,
                       const __hip_bfloat16* __restrict__ cfl,
                       const float* __restrict__ starts,
                       float* __restrict__ out) {
  __shared__ float red[2];
  int b = blockIdx.x, tid = threadIdx.x; // 128
  long cell = dBase(cL - 1) + b;
  float v = chart_p[cell * cS + tid] * starts[tid];
  #pragma unroll
  for (int off = 1; off < 64; off <<= 1) v += __shfl_xor(v, off, 64);
  if ((tid & 63) == 0) red[tid >> 6] = v;
  __syncthreads();
  float score = red[0] + red[1];
  size_t fbase = (size_t)cell * cSD;
  for (int h = tid; h < cSD; h += 128) {
    float f = __bfloat162float(cfh[fbase + h]) + __bfloat162float(cfl[fbase + h]);
    out[(size_t)b * cSD + h] = f * score;
  }
}

extern "C" void kernel_launch(void* const* d_in, const int* in_sizes, int n_in,
                              void* d_out, int out_size, void* d_ws, size_t ws_size,
                              hipStream_t stream) {
  const int* word = (const int*)d_in[0];
  const float* WE = (const float*)d_in[1];
  const float* preterm = (const float*)d_in[2];
  const float* G = (const float*)d_in[3];
  const float* starts = (const float*)d_in[4];
  const float* Wp = (const float*)d_in[5];
  const float* bp = (const float*)d_in[6];
  const float* Wm = (const float*)d_in[7];
  const float* bm = (const float*)d_in[8];
  float* out = (float*)d_out;
  float* ws = (float*)d_ws;

  size_t off = 0;
  float* chart_p = ws + off; off += (size_t)TRIC * cS;           // 17.3 MB
  float* chart_v = ws + off; off += (size_t)TRIC * cS;           // 17.3 MB
  __hip_bfloat16* cfh = (__hip_bfloat16*)(ws + off); off += (size_t)TRIC * cSD / 2; // 34.6 MB
  __hip_bfloat16* cfl = (__hip_bfloat16*)(ws + off); off += (size_t)TRIC * cSD / 2; // 34.6 MB
  float* Gll = ws + off; off += (size_t)cKQ * cNT;               // 1 MB
  float* Ghh = ws + off; off += (size_t)cKQ * cNT;               // 1 MB
  float* GsumT = ws + off; off += cS * cS;
  float* e_arr = ws + off; off += (size_t)2048 * 4096;           // 33.5 MB
  float* f_arr = ws + off; off += (size_t)2048 * 4096;           // 33.5 MB
  __hip_bfloat16* WmTh = (__hip_bfloat16*)(ws + off); off += (size_t)cSD * 1024 / 2;
  __hip_bfloat16* WmTl = (__hip_bfloat16*)(ws + off); off += (size_t)cSD * 1024 / 2;
  float* uv = ws + off; off += (size_t)TRIC * 1024;              // 138.4 MB packed
  float* Obuf0 = ws + off; off += (size_t)CHpad * cKQ;           // 32.5 MB
  float* Obuf1 = ws + off; off += (size_t)CHpad * cKQ;           // 32.5 MB
  float* scoresP = ws + off; off += (size_t)CHpad * KS * cNT;    // 8.1 MB
  // total ~386.7 MB <= 409.6 MB (measured via harness fill WRITE_SIZE)

  auto hdB = [](int d) { return (long)cB * ((long)d * cL - (long)d * (d - 1) / 2); };

  // S1: prep_g(64) || prep_wmt(2048) || diag_p(1024, 2 cells/blk) || feat0(256)
  k_S1<<<64 + 2048 + 1024 + 256, 256, 0, stream>>>(
      G, Gll, Ghh, GsumT, Wm, WmTh, WmTl, word, preterm, chart_p,
      WE, Wp, bp, cfh, cfl);
  // S2: prep_e(2048) || prep_f(1024) || uv(diag0,128) || outer(ln=2,1984)
  //     || diag_v(1024, 2 cells/blk = all 2048 diag-0 cells)
  k_S2<<<2048 + 1024 + 128 + 1984 + 1024, 256, 0, stream>>>(
      chart_p, G, e_arr, f_arr, cfh, cfl, WmTh, WmTl, uv, Obuf0, GsumT, chart_v);

  for (int ln = 2; ln <= cL; ++ln) {
    int n = cL - ln + 1, Bn = cB * n;
    int useGemm = (ln == 2 || ln >= 4) ? 1 : 0;
    int useEF = (ln >= 3) ? 1 : 0;
    int gx = useGemm ? (Bn + 127) / 128 : 0;
    int sB = gx * KS;
    int Mu = (ln >= 3) ? cB * (cL - (ln - 2)) : 0;    // cells of diag ln-2
    int uB = (ln >= 3) ? ((Mu + 127) / 128) * 8 : 0;
    int oR = (ln >= 3 && ln <= cL - 1) ? cB * (cL - ln) : 0; // rows of diag ln+1
    const float* Oin = (ln & 1) ? Obuf1 : Obuf0;
    float* Oout = ((ln + 1) & 1) ? Obuf1 : Obuf0;
    // X(ln): scores(ln) || uv(diag ln-2) || outer(ln+1)
    if (sB + uB + oR > 0)
      k_X<<<sB + uB + oR, 256, 0, stream>>>(
          Oin, (ln == 2) ? Ghh : Gll, scoresP, gx, Bn, sB,
          cfh, cfl, WmTh, WmTl, uv, hdB(ln - 2), Mu, uB,
          chart_p, Oout, ln + 1, cL - ln, 1, ln - 2);
    // Y(ln): normp(ln) || combine(ln) [h-split x2]
    k_Y<<<3 * Bn, 256, 0, stream>>>(
        scoresP, e_arr, f_arr, GsumT, chart_p, chart_v,
        uv, bm, cfh, cfl, ln, n, useGemm, useEF, Bn);
  }

  k_root<<<cB, 128, 0, stream>>>(chart_p, cfh, cfl, starts, out);
}

// Round 9
// 1492.506 us; speedup vs baseline: 1.3047x; 1.2696x over previous
//
#include <hip/hip_runtime.h>
#include <hip/hip_bf16.h>

// CYK forward. p-chain fp32 (scores GEMM bf16x3-MFMA, error ~1e-7 rel);
// f-chain GEMM bf16x3 MFMA.
// Round 16:
//  (1) S2 split: S2a = prep_e||prep_f||diag_v (8.7KB LDS, high occupancy,
//      streaming) + S2b = uv(diag0)||outer(ln=2) (40KB). Round-15's merged
//      S2 ran streaming roles at 20% occupancy (78.6us top dispatch).
//  (2) combine h-split x2 only when Bn<=512 (late diagonals); early
//      diagonals 1 block/row (halves mass-read traffic there).
//  (3) scores GEMM fp32-VALU -> bf16x3 MFMA (the f-chain's verified
//      scheme): outer emits O as bf16 hi/lo planes (same bytes as fp32),
//      G quadrants pre-transposed [a][k] bf16 hi/lo, scores role mirrors
//      uv_body's fragment algebra. 16.6GF fp32 -> 50GF MFMA.

typedef __attribute__((ext_vector_type(8))) short short8;
typedef __attribute__((ext_vector_type(4))) float f32x4;

constexpr int cB = 64, cL = 32, cNT = 64, cS = 128, cV = 50000;
constexpr int cEMB = 512, cSD = 512, cKQ = 4096; // quadrant k
constexpr int DMAX = 31, KS = 16;                // k-slice = 256
constexpr int CHpad = 1984;
constexpr float cEPS = 1e-9f;
constexpr long TRIC = (long)cB * (cL * (cL + 1) / 2); // 33792 packed cells

__device__ __forceinline__ long dBase(int d) {
  return (long)cB * ((long)d * cL - ((long)d * (d - 1)) / 2);
}

__device__ __forceinline__ void split_bf16(float x, __hip_bfloat16& h, __hip_bfloat16& l) {
  h = __float2bfloat16(x);
  l = __float2bfloat16(x - __bfloat162float(h));
}

// ---------------- fp32 GEMM micro ----------------
__device__ __forceinline__ void micro16(const float (*As)[68], const float (*Bs)[68],
                                        int r0, int c0, float acc[4][4]) {
  #pragma unroll
  for (int k = 0; k < 16; ++k) {
    float4 a4 = *(const float4*)&As[k][r0];
    float4 b4 = *(const float4*)&Bs[k][c0];
    float ar[4] = {a4.x, a4.y, a4.z, a4.w};
    float br[4] = {b4.x, b4.y, b4.z, b4.w};
    #pragma unroll
    for (int i = 0; i < 4; ++i)
      #pragma unroll
      for (int j = 0; j < 4; ++j)
        acc[i][j] = fmaf(ar[i], br[j], acc[i][j]);
  }
}

// ---------------- uv GEMM body (bf16x3 MFMA, 128x128 tile, K=512) ----------------
__device__ __forceinline__ void uv_body(
    char* smraw, int tid, int ubid,
    const __hip_bfloat16* __restrict__ cfh, const __hip_bfloat16* __restrict__ cfl,
    const __hip_bfloat16* __restrict__ WmTh, const __hip_bfloat16* __restrict__ WmTl,
    float* __restrict__ uv, long cellBase, int M) {
  short* Ash = (short*)smraw;              // [2*128][40]
  short* Bsh = (short*)(smraw + 20480);    // [2*128][40]
  int colTile = (ubid & 7) << 7;
  int rowTile = (ubid >> 3) << 7;
  int m0 = tid >> 2, kq8 = (tid & 3) * 8;

  long offA[2];
  #pragma unroll
  for (int h = 0; h < 2; ++h) {
    int row = rowTile + m0 + h * 64;
    if (row >= M) row = M - 1;
    offA[h] = (cellBase + row) * cSD;
  }
  long offB0 = (long)(colTile + m0) * 512;
  long offB1 = (long)(colTile + m0 + 64) * 512;

  f32x4 acc[4][4];
  f32x4 zero = {0.f, 0.f, 0.f, 0.f};
  #pragma unroll
  for (int a_ = 0; a_ < 4; ++a_)
    #pragma unroll
    for (int b_ = 0; b_ < 4; ++b_) acc[a_][b_] = zero;

  int lane = tid & 63, wid = tid >> 6;
  int wm = wid >> 1, wn = wid & 1;
  int fr = lane & 15, fq = lane >> 4;

  int4 pA0h = *(const int4*)(const void*)(cfh + offA[0] + kq8);
  int4 pA1h = *(const int4*)(const void*)(cfh + offA[1] + kq8);
  int4 pA0l = *(const int4*)(const void*)(cfl + offA[0] + kq8);
  int4 pA1l = *(const int4*)(const void*)(cfl + offA[1] + kq8);
  int4 pB0h = *(const int4*)(const void*)(WmTh + offB0 + kq8);
  int4 pB1h = *(const int4*)(const void*)(WmTh + offB1 + kq8);
  int4 pB0l = *(const int4*)(const void*)(WmTl + offB0 + kq8);
  int4 pB1l = *(const int4*)(const void*)(WmTl + offB1 + kq8);

  for (int kb = 0; kb < 512; kb += 32) {
    __syncthreads();
    *(int4*)&Ash[(0 * 128 + m0) * 40 + kq8] = pA0h;
    *(int4*)&Ash[(0 * 128 + m0 + 64) * 40 + kq8] = pA1h;
    *(int4*)&Ash[(1 * 128 + m0) * 40 + kq8] = pA0l;
    *(int4*)&Ash[(1 * 128 + m0 + 64) * 40 + kq8] = pA1l;
    *(int4*)&Bsh[(0 * 128 + m0) * 40 + kq8] = pB0h;
    *(int4*)&Bsh[(0 * 128 + m0 + 64) * 40 + kq8] = pB1h;
    *(int4*)&Bsh[(1 * 128 + m0) * 40 + kq8] = pB0l;
    *(int4*)&Bsh[(1 * 128 + m0 + 64) * 40 + kq8] = pB1l;
    __syncthreads();
    int kn = kb + 32;
    if (kn < 512) {
      pA0h = *(const int4*)(const void*)(cfh + offA[0] + kn + kq8);
      pA1h = *(const int4*)(const void*)(cfh + offA[1] + kn + kq8);
      pA0l = *(const int4*)(const void*)(cfl + offA[0] + kn + kq8);
      pA1l = *(const int4*)(const void*)(cfl + offA[1] + kn + kq8);
      pB0h = *(const int4*)(const void*)(WmTh + offB0 + kn + kq8);
      pB1h = *(const int4*)(const void*)(WmTh + offB1 + kn + kq8);
      pB0l = *(const int4*)(const void*)(WmTl + offB0 + kn + kq8);
      pB1l = *(const int4*)(const void*)(WmTl + offB1 + kn + kq8);
    }
    short8 af[2][4], bf[2][4];
    #pragma unroll
    for (int pl = 0; pl < 2; ++pl)
      #pragma unroll
      for (int mf = 0; mf < 4; ++mf)
        af[pl][mf] = *(const short8*)&Ash[(pl * 128 + wm * 64 + mf * 16 + fr) * 40 + fq * 8];
    #pragma unroll
    for (int pl = 0; pl < 2; ++pl)
      #pragma unroll
      for (int nf = 0; nf < 4; ++nf)
        bf[pl][nf] = *(const short8*)&Bsh[(pl * 128 + wn * 64 + nf * 16 + fr) * 40 + fq * 8];
    #pragma unroll
    for (int mf = 0; mf < 4; ++mf)
      #pragma unroll
      for (int nf = 0; nf < 4; ++nf) {
        acc[mf][nf] = __builtin_amdgcn_mfma_f32_16x16x32_bf16(af[0][mf], bf[0][nf], acc[mf][nf], 0, 0, 0);
        acc[mf][nf] = __builtin_amdgcn_mfma_f32_16x16x32_bf16(af[0][mf], bf[1][nf], acc[mf][nf], 0, 0, 0);
        acc[mf][nf] = __builtin_amdgcn_mfma_f32_16x16x32_bf16(af[1][mf], bf[0][nf], acc[mf][nf], 0, 0, 0);
      }
  }
  #pragma unroll
  for (int mf = 0; mf < 4; ++mf)
    #pragma unroll
    for (int r = 0; r < 4; ++r) {
      int row = rowTile + wm * 64 + mf * 16 + fq * 4 + r;
      if (row >= M) continue;
      float* op = uv + (cellBase + row) * 1024 + colTile + wn * 64;
      #pragma unroll
      for (int nf = 0; nf < 4; ++nf)
        op[nf * 16 + fr] = acc[mf][nf][r];
    }
}

// ---------------- outer-product body (emits bf16 hi/lo planes) ----------------
__device__ __forceinline__ void outer_body(
    char* smraw, int tid, int lr, const float* __restrict__ chart_p,
    __hip_bfloat16* __restrict__ OoutH, __hip_bfloat16* __restrict__ OoutL,
    int oln, int on, int odlo, int odhi, int osoff, int otoff) {
  float* lp = (float*)smraw;                  // [DMAX][64]
  float* rp = (float*)(smraw + DMAX * 64 * 4);
  int b = lr / on, i = lr - b * on;
  if (tid < 128) {
    int lane = tid & 63;
    for (int dd = odlo + (tid >> 6); dd <= odhi; dd += 2) {
      long lc = dBase(dd) + (long)b * (cL - dd) + i;
      lp[(dd - odlo) * 64 + lane] = chart_p[lc * cS + osoff + lane];
    }
  } else {
    int t2 = tid - 128;
    int lane = t2 & 63;
    for (int dd = odlo + (t2 >> 6); dd <= odhi; dd += 2) {
      int dr = oln - dd - 2;
      long rc = dBase(dr) + (long)b * (cL - dr) + (i + dd + 1);
      rp[(dd - odlo) * 64 + lane] = chart_p[rc * cS + otoff + lane];
    }
  }
  __syncthreads();
  float acc[16];
  #pragma unroll
  for (int j = 0; j < 16; ++j) acc[j] = 0.f;
  int s = tid >> 2, t0 = (tid & 3) << 4;
  int dcount = odhi - odlo + 1;
  for (int dd = 0; dd < dcount; ++dd) {
    float lps = lp[dd * 64 + s];
    #pragma unroll
    for (int qq = 0; qq < 4; ++qq) {
      float4 r4 = *(const float4*)&rp[dd * 64 + t0 + qq * 4];
      acc[qq * 4 + 0] = fmaf(lps, r4.x, acc[qq * 4 + 0]);
      acc[qq * 4 + 1] = fmaf(lps, r4.y, acc[qq * 4 + 1]);
      acc[qq * 4 + 2] = fmaf(lps, r4.z, acc[qq * 4 + 2]);
      acc[qq * 4 + 3] = fmaf(lps, r4.w, acc[qq * 4 + 3]);
    }
  }
  size_t base = (size_t)lr * cKQ + (size_t)tid * 16; // p = s*64+t
  __hip_bfloat16 hv[16], lv[16];
  #pragma unroll
  for (int j = 0; j < 16; ++j) split_bf16(acc[j], hv[j], lv[j]);
  #pragma unroll
  for (int j = 0; j < 16; ++j) {
    OoutH[base + j] = hv[j];
    OoutL[base + j] = lv[j];
  }
}

// ---------------- S1: prep_g || prep_wmt || diag_p || feat0 ----------------
// prep_g emits G quadrants TRANSPOSED [a][p] as bf16 hi/lo (MFMA B-operand
// layout) + GsumT. diag_p writes chart_p ONLY (diag-0 chart_v in S2a).
__global__ __launch_bounds__(256) void k_S1(
    const float* __restrict__ G,
    __hip_bfloat16* __restrict__ GllTh, __hip_bfloat16* __restrict__ GllTl,
    __hip_bfloat16* __restrict__ GhhTh, __hip_bfloat16* __restrict__ GhhTl,
    float* __restrict__ GsumT, const float* __restrict__ Wm,
    __hip_bfloat16* __restrict__ WmTh, __hip_bfloat16* __restrict__ WmTl,
    const int* __restrict__ word, const float* __restrict__ preterm,
    float* __restrict__ chart_p,
    const float* __restrict__ WE, const float* __restrict__ Wp,
    const float* __restrict__ bp,
    __hip_bfloat16* __restrict__ cfh, __hip_bfloat16* __restrict__ cfl) {
  __shared__ __align__(16) char smraw[8704];
  int bid = blockIdx.x, tid = threadIdx.x;
  if (bid < 64) {
    // prep_g
    int idx = bid * 256 + tid; // s*128+t
    int s = idx >> 7, t = idx & 127;
    bool lo = (s < 64) && (t < 64);
    bool hi = (s >= 64) && (t >= 64);
    int pl = s * 64 + t;
    int ph = (s - 64) * 64 + (t - 64);
    float accum = 0.f;
    for (int a = 0; a < cNT; ++a) {
      float g = G[(size_t)a * 16384 + idx];
      accum += g;
      __hip_bfloat16 gh, gl;
      split_bf16(g, gh, gl);
      if (lo) { GllTh[(size_t)a * cKQ + pl] = gh; GllTl[(size_t)a * cKQ + pl] = gl; }
      if (hi) { GhhTh[(size_t)a * cKQ + ph] = gh; GhhTl[(size_t)a * cKQ + ph] = gl; }
    }
    GsumT[t * cS + s] = accum;
  } else if (bid < 64 + 2048) {
    // prep_wmt: layout [nn<1024][k<512]
    int idx = (bid - 64) * 256 + tid; // nn*512 + k
    int k = idx & 511, nn = idx >> 9;
    int krow = k + ((nn >= 512) ? 512 : 0);
    float v = Wm[(size_t)krow * cSD + (nn & 511)];
    __hip_bfloat16 h, l;
    split_bf16(v, h, l);
    WmTh[idx] = h;
    WmTl[idx] = l;
  } else if (bid < 64 + 2048 + 1024) {
    // diag_p: 2 cells per block; chart_p only
    int dbid = bid - (64 + 2048);
    int rsel = tid >> 7, t = tid & 127;
    int r2 = dbid * 2 + rsel;
    int w = word[r2];
    float val = (t >= 64) ? preterm[(size_t)(t - 64) * cV + w] : 0.f;
    float sum = val;
    #pragma unroll
    for (int off = 1; off < 64; off <<= 1) sum += __shfl_xor(sum, off, 64);
    float p_ = (t >= 64) ? val / (sum + cEPS) : 0.f;
    chart_p[(size_t)r2 * cS + t] = p_;
  } else {
    // feat0
    float (*As)[68] = (float (*)[68])smraw;
    float (*Bs)[68] = (float (*)[68])(smraw + 4352);
    int fb = bid - (64 + 2048 + 1024);
    int rowTile = (fb >> 3) * 64;
    int n0 = (fb & 7) * 64;
    int lr = tid >> 2, lk = (tid & 3) << 2;
    int bk = tid >> 4, bn = (tid & 15) << 2;
    int r0 = (tid >> 4) << 2, c0 = (tid & 15) << 2;
    const float* ap = WE + (size_t)word[rowTile + lr] * cEMB;
    float acc[4][4] = {};
    for (int kb = 0; kb < cEMB; kb += 16) {
      float4 av = *(const float4*)(ap + kb + lk);
      float4 bv = *(const float4*)(Wp + (size_t)(kb + bk) * cSD + n0 + bn);
      __syncthreads();
      As[lk + 0][lr] = av.x; As[lk + 1][lr] = av.y;
      As[lk + 2][lr] = av.z; As[lk + 3][lr] = av.w;
      *(float4*)&Bs[bk][bn] = bv;
      __syncthreads();
      micro16(As, Bs, r0, c0, acc);
    }
    float4 bpv = *(const float4*)(bp + n0 + c0);
    float bpr[4] = {bpv.x, bpv.y, bpv.z, bpv.w};
    #pragma unroll
    for (int i = 0; i < 4; ++i) {
      int row = rowTile + r0 + i; // packed diag-0 cell
      size_t base = (size_t)row * cSD + n0 + c0;
      #pragma unroll
      for (int e = 0; e < 4; ++e) {
        float v = fmaxf(acc[i][e] + bpr[e], 0.f);
        __hip_bfloat16 h, l;
        split_bf16(v, h, l);
        cfh[base + e] = h;
        cfl[base + e] = l;
      }
    }
  }
}

// ---------------- S2a: prep_e || prep_f || diag_v (light LDS, streaming) ----------------
__global__ __launch_bounds__(256) void k_S2a(
    const float* __restrict__ chart_p, const float* __restrict__ G,
    float* __restrict__ e_arr, float* __restrict__ f_arr,
    const float* __restrict__ GsumT, float* __restrict__ chart_v) {
  __shared__ __align__(16) char smraw[8704];
  int bid = blockIdx.x, tid = threadIdx.x;
  if (bid < 2048) {
    // prep_e: e[cell][a][t_lo] = sum_s p_hi[s] G[a][64+s][t]
    float (*As)[68] = (float (*)[68])smraw;
    float (*Bs)[68] = (float (*)[68])(smraw + 4352);
    int rowTile = (bid & 31) * 64;
    int n0 = (bid >> 5) * 64;
    int a = n0 >> 6;
    int lr = tid >> 2, lk = (tid & 3) << 2;
    int bk = tid >> 4, bn = (tid & 15) << 2;
    int r0 = (tid >> 4) << 2, c0 = (tid & 15) << 2;
    float acc[4][4] = {};
    for (int kb = 0; kb < 64; kb += 16) {
      float4 av = *(const float4*)(chart_p + (size_t)(rowTile + lr) * cS + 64 + kb + lk);
      float4 bv = *(const float4*)(G + (size_t)a * 16384 + (size_t)(64 + kb + bk) * 128 + bn);
      __syncthreads();
      As[lk + 0][lr] = av.x; As[lk + 1][lr] = av.y;
      As[lk + 2][lr] = av.z; As[lk + 3][lr] = av.w;
      *(float4*)&Bs[bk][bn] = bv;
      __syncthreads();
      micro16(As, Bs, r0, c0, acc);
    }
    #pragma unroll
    for (int i = 0; i < 4; ++i) {
      float4 o = {acc[i][0], acc[i][1], acc[i][2], acc[i][3]};
      *(float4*)&e_arr[(size_t)(rowTile + r0 + i) * 4096 + n0 + c0] = o;
    }
  } else if (bid < 3072) {
    // prep_f: f[cell][a][s_lo] = sum_t G[a][s][64+t] p_hi[t]
    float* ph = (float*)smraw; // [8][64]
    int fb = bid - 2048;
    int cell0 = (fb & 255) * 8;
    for (int v = tid; v < 512; v += 256) {
      int cc = v >> 6, t = v & 63;
      ph[cc * 64 + t] = chart_p[(size_t)(cell0 + cc) * cS + 64 + t];
    }
    __syncthreads();
    int oo0 = (fb >> 8) * 4;
    for (int oo = oo0; oo < oo0 + 4; ++oo) {
      int out_id = oo * 256 + tid; // a*64 + s
      int a = out_id >> 6, s = out_id & 63;
      const float* gb = G + (size_t)a * 16384 + (size_t)s * 128 + 64;
      float acc[8] = {};
      #pragma unroll 4
      for (int ch = 0; ch < 16; ++ch) {
        float4 g4 = *(const float4*)(gb + ch * 4);
        #pragma unroll
        for (int cc = 0; cc < 8; ++cc) {
          float4 p4 = *(const float4*)&ph[cc * 64 + ch * 4];
          acc[cc] = fmaf(g4.x, p4.x, acc[cc]);
          acc[cc] = fmaf(g4.y, p4.y, acc[cc]);
          acc[cc] = fmaf(g4.z, p4.z, acc[cc]);
          acc[cc] = fmaf(g4.w, p4.w, acc[cc]);
        }
      }
      #pragma unroll
      for (int cc = 0; cc < 8; ++cc)
        f_arr[(size_t)(cell0 + cc) * 4096 + out_id] = acc[cc];
    }
  } else {
    // diag_v: chart_v for diag 0 (2 cells/block, 1024 blocks = 2048 cells);
    // reads S1's GsumT + chart_p (cross-kernel dependency, legal)
    float* ps = (float*)smraw; // [2][64]
    int vb = bid - 3072;
    int rsel = tid >> 7, t = tid & 127;
    size_t base = (size_t)(vb * 2 + rsel) * cS;
    if (t >= 64) ps[rsel * 64 + (t - 64)] = chart_p[base + t];
    __syncthreads();
    float v = 0.f;
    for (int t2 = 0; t2 < 64; ++t2)
      v = fmaf(GsumT[(t2 + 64) * cS + t], ps[rsel * 64 + t2], v);
    chart_v[base + t] = v;
  }
}

// ---------------- S2b: uv(diag0) || outer(ln=2) (40KB LDS) ----------------
__global__ __launch_bounds__(256) void k_S2b(
    const float* __restrict__ chart_p,
    const __hip_bfloat16* __restrict__ cfh, const __hip_bfloat16* __restrict__ cfl,
    const __hip_bfloat16* __restrict__ WmTh, const __hip_bfloat16* __restrict__ WmTl,
    float* __restrict__ uv,
    __hip_bfloat16* __restrict__ Oh0, __hip_bfloat16* __restrict__ Ol0) {
  __shared__ __align__(16) char smraw[40960];
  int bid = blockIdx.x, tid = threadIdx.x;
  if (bid < 128) {
    uv_body(smraw, tid, bid, cfh, cfl, WmTh, WmTl, uv, 0L, 2048);
  } else {
    outer_body(smraw, tid, bid - 128, chart_p, Oh0, Ol0, 2, 31, 0, 0, 64, 64);
  }
}

// ---------------- X: scores MFMA || uv(diag ln-2) || outer(ln+1) ----------------
// scores: Oin(bf16 h/l) @ GqT(bf16 h/l), bf16x3, 128x64 tile, k-slice 256.
// All roles depend only on Y(ln-1); Oin/Oout parity double-buffered.
__global__ __launch_bounds__(256) void k_X(
    const __hip_bfloat16* __restrict__ OinH, const __hip_bfloat16* __restrict__ OinL,
    const __hip_bfloat16* __restrict__ GqTh, const __hip_bfloat16* __restrict__ GqTl,
    float* __restrict__ scoresP, int gx, int sRows, int sB,
    const __hip_bfloat16* __restrict__ cfh, const __hip_bfloat16* __restrict__ cfl,
    const __hip_bfloat16* __restrict__ WmTh, const __hip_bfloat16* __restrict__ WmTl,
    float* __restrict__ uv, long uvCellBase, int uvM, int uB,
    const float* __restrict__ chart_p,
    __hip_bfloat16* __restrict__ OoutH, __hip_bfloat16* __restrict__ OoutL,
    int oln, int on, int odlo, int odhi) {
  __shared__ __align__(16) char smraw[40960];
  int bid = blockIdx.x;
  int tid = threadIdx.x;
  if (bid < sB) {
    // ======== scores MFMA role (mirrors uv_body's verified algebra) ========
    short* Ash = (short*)smraw;              // [2*128][40]
    short* Bsh = (short*)(smraw + 20480);    // [2*64][40]
    int rt = bid % gx, ks = bid / gx;
    int rowTile = rt * 128;
    int kstart = ks * 256;
    int m0 = tid >> 2, kq8 = (tid & 3) * 8;
    int r0c = rowTile + m0;       if (r0c >= sRows) r0c = sRows - 1;
    int r1c = rowTile + m0 + 64;  if (r1c >= sRows) r1c = sRows - 1;
    long offA0 = (long)r0c * cKQ + kstart;
    long offA1 = (long)r1c * cKQ + kstart;
    long offB = (long)m0 * cKQ + kstart;

    f32x4 acc[4][2];
    f32x4 zero = {0.f, 0.f, 0.f, 0.f};
    #pragma unroll
    for (int a_ = 0; a_ < 4; ++a_)
      #pragma unroll
      for (int b_ = 0; b_ < 2; ++b_) acc[a_][b_] = zero;

    int lane = tid & 63, wid = tid >> 6;
    int wm = wid >> 1, wn = wid & 1;
    int fr = lane & 15, fq = lane >> 4;

    int4 pA0h = *(const int4*)(const void*)(OinH + offA0 + kq8);
    int4 pA1h = *(const int4*)(const void*)(OinH + offA1 + kq8);
    int4 pA0l = *(const int4*)(const void*)(OinL + offA0 + kq8);
    int4 pA1l = *(const int4*)(const void*)(OinL + offA1 + kq8);
    int4 pBh = *(const int4*)(const void*)(GqTh + offB + kq8);
    int4 pBl = *(const int4*)(const void*)(GqTl + offB + kq8);

    for (int kb = 0; kb < 256; kb += 32) {
      __syncthreads();
      *(int4*)&Ash[(0 * 128 + m0) * 40 + kq8] = pA0h;
      *(int4*)&Ash[(0 * 128 + m0 + 64) * 40 + kq8] = pA1h;
      *(int4*)&Ash[(1 * 128 + m0) * 40 + kq8] = pA0l;
      *(int4*)&Ash[(1 * 128 + m0 + 64) * 40 + kq8] = pA1l;
      *(int4*)&Bsh[(0 * 64 + m0) * 40 + kq8] = pBh;
      *(int4*)&Bsh[(1 * 64 + m0) * 40 + kq8] = pBl;
      __syncthreads();
      int kn = kb + 32;
      if (kn < 256) {
        pA0h = *(const int4*)(const void*)(OinH + offA0 + kn + kq8);
        pA1h = *(const int4*)(const void*)(OinH + offA1 + kn + kq8);
        pA0l = *(const int4*)(const void*)(OinL + offA0 + kn + kq8);
        pA1l = *(const int4*)(const void*)(OinL + offA1 + kn + kq8);
        pBh = *(const int4*)(const void*)(GqTh + offB + kn + kq8);
        pBl = *(const int4*)(const void*)(GqTl + offB + kn + kq8);
      }
      short8 af[2][4], bf[2][2];
      #pragma unroll
      for (int pl = 0; pl < 2; ++pl)
        #pragma unroll
        for (int mf = 0; mf < 4; ++mf)
          af[pl][mf] = *(const short8*)&Ash[(pl * 128 + wm * 64 + mf * 16 + fr) * 40 + fq * 8];
      #pragma unroll
      for (int pl = 0; pl < 2; ++pl)
        #pragma unroll
        for (int nf = 0; nf < 2; ++nf)
          bf[pl][nf] = *(const short8*)&Bsh[(pl * 64 + wn * 32 + nf * 16 + fr) * 40 + fq * 8];
      #pragma unroll
      for (int mf = 0; mf < 4; ++mf)
        #pragma unroll
        for (int nf = 0; nf < 2; ++nf) {
          acc[mf][nf] = __builtin_amdgcn_mfma_f32_16x16x32_bf16(af[0][mf], bf[0][nf], acc[mf][nf], 0, 0, 0);
          acc[mf][nf] = __builtin_amdgcn_mfma_f32_16x16x32_bf16(af[0][mf], bf[1][nf], acc[mf][nf], 0, 0, 0);
          acc[mf][nf] = __builtin_amdgcn_mfma_f32_16x16x32_bf16(af[1][mf], bf[0][nf], acc[mf][nf], 0, 0, 0);
        }
    }
    #pragma unroll
    for (int mf = 0; mf < 4; ++mf)
      #pragma unroll
      for (int nf = 0; nf < 2; ++nf) {
        int col = wn * 32 + nf * 16 + fr;
        #pragma unroll
        for (int r = 0; r < 4; ++r) {
          int row = rowTile + wm * 64 + mf * 16 + fq * 4 + r;
          if (row < sRows)
            scoresP[((size_t)ks * CHpad + row) * cNT + col] = acc[mf][nf][r];
        }
      }
  } else if (bid < sB + uB) {
    uv_body(smraw, tid, bid - sB, cfh, cfl, WmTh, WmTl, uv, uvCellBase, uvM);
  } else {
    outer_body(smraw, tid, bid - sB - uB, chart_p, OoutH, OoutL, oln, on, odlo, odhi, 0, 0);
  }
}

// ---------------- Y: normp || combine (both light; 2.3KB LDS) ----------------
__global__ __launch_bounds__(256) void k_Y(
    const float* __restrict__ scoresP, const float* __restrict__ e_arr,
    const float* __restrict__ f_arr, const float* __restrict__ GsumT,
    float* __restrict__ chart_p, float* __restrict__ chart_v,
    const float* __restrict__ uv, const float* __restrict__ bm,
    __hip_bfloat16* __restrict__ cfh, __hip_bfloat16* __restrict__ cfl,
    int ln, int nn, int useGemm, int useEF, int Bn, int hsplit) {
  __shared__ __align__(16) char smraw[2304];
  int bid = blockIdx.x, tid = threadIdx.x;
  if (bid < Bn) {
    // ======== normp role (4-way lane-parallel) ========
    float* sP = (float*)smraw;             // 128 floats
    float* part = sP + 128;                // [4][64]
    float* ps = part + 256;                // 64
    int row = bid;
    int b = row / nn, i = row - b * nn;
    if (useEF) {
      long c2 = dBase(ln - 2) + (long)b * (nn + 1); // width at diag ln-2 is nn+1
      if (tid < 64)
        sP[tid] = chart_p[(c2 + i + 1) * cS + tid];
      else if (tid < 128)
        sP[tid] = chart_p[(c2 + i) * cS + (tid - 64)];
      __syncthreads();
    }
    int a = tid & 63, g = tid >> 6;
    float val = 0.f;
    if (useGemm) {
      #pragma unroll
      for (int ks = g * 4; ks < g * 4 + 4; ++ks)
        val += scoresP[((size_t)ks * CHpad + row) * cNT + a];
    }
    if (useEF) {
      const float4* e4 = (const float4*)&e_arr[((size_t)(b * cL + i) * 4096) + a * 64];
      const float4* f4 = (const float4*)&f_arr[((size_t)(b * cL + i + ln - 1) * 4096) + a * 64];
      const float4* sP4 = (const float4*)sP;
      #pragma unroll
      for (int q = g * 4; q < g * 4 + 4; ++q) {
        float4 ev = e4[q];
        float4 fv = f4[q];
        float4 rv = sP4[q];
        float4 lv = sP4[16 + q];
        val = fmaf(ev.x, rv.x, val); val = fmaf(ev.y, rv.y, val);
        val = fmaf(ev.z, rv.z, val); val = fmaf(ev.w, rv.w, val);
        val = fmaf(fv.x, lv.x, val); val = fmaf(fv.y, lv.y, val);
        val = fmaf(fv.z, lv.z, val); val = fmaf(fv.w, lv.w, val);
      }
    }
    part[g * 64 + a] = val;
    __syncthreads();
    size_t base = (size_t)(dBase(ln - 1) + row) * cS;
    if (tid < 64) {
      float v = part[a] + part[64 + a] + part[128 + a] + part[192 + a];
      float sum = v;
      #pragma unroll
      for (int off = 1; off < 64; off <<= 1) sum += __shfl_xor(sum, off, 64);
      float p_ = v / (sum + cEPS);
      ps[a] = p_;
      chart_p[base + tid] = p_;
    } else if (tid < 128) {
      chart_p[base + tid] = 0.f;
    }
    __syncthreads();
    if (tid < 128) {
      float v = 0.f;
      for (int t = 0; t < 64; ++t) v = fmaf(GsumT[t * cS + tid], ps[t], v);
      chart_v[base + tid] = v;
    }
  } else {
    // ======== combine role (conditional h-split; one-shot masses) ========
    long* loff = (long*)smraw;                 // 32 longs
    long* roff = loff + 32;
    long* lpcS = roff + 32;
    long* vpcS = lpcS + 32;                    // ends at 1024 B
    float* lm = (float*)(smraw + 1024);        // 31 floats (pad to 1152)
    float* part8 = (float*)(smraw + 1152);     // [32][8] floats -> ends 2176
    int cbid = bid - Bn;
    int row = hsplit ? (cbid >> 1) : cbid;
    int hs = hsplit ? (cbid & 1) : 0;
    int D = ln - 1;
    int b = row / nn, i = row - b * nn;
    if (tid < D) {
      int dd = tid;
      long lc = dBase(dd) + (long)b * (cL - dd) + i;
      int dr = ln - dd - 2;
      long rc = dBase(dr) + (long)b * (cL - dr) + (i + dd + 1);
      loff[dd] = lc * 1024;        // u half
      roff[dd] = rc * 1024 + 512;  // v half
      lpcS[dd] = lc * cS;
      vpcS[dd] = rc * cS;
    }
    __syncthreads();
    int dd8 = tid >> 3, sl = (tid & 7) << 4;
    float prt = 0.f;
    if (dd8 < D) {
      const float* pp = &chart_p[lpcS[dd8] + sl];
      const float* vv = &chart_v[vpcS[dd8] + sl];
      #pragma unroll
      for (int q = 0; q < 4; ++q) {
        float4 p4 = *(const float4*)(pp + q * 4);
        float4 v4 = *(const float4*)(vv + q * 4);
        prt = fmaf(p4.x, v4.x, prt); prt = fmaf(p4.y, v4.y, prt);
        prt = fmaf(p4.z, v4.z, prt); prt = fmaf(p4.w, v4.w, prt);
      }
    }
    part8[dd8 * 8 + (tid & 7)] = prt;
    __syncthreads();
    if (tid < D) {
      float s = 0.f;
      #pragma unroll
      for (int j = 0; j < 8; ++j) s += part8[tid * 8 + j];
      lm[tid] = s;
    }
    __syncthreads();
    float msum = 0.f;
    for (int dd = 0; dd < D; ++dd) msum += lm[dd];
    float inv = 1.f / (msum + cEPS);
    size_t outbase = (size_t)(dBase(ln - 1) + row) * cSD;
    int hn = hsplit ? 256 : 512;
    int hbase = hs * 256;
    for (int hh = 0; hh < hn; hh += 256) {
      int h = hbase + hh + tid;
      float bmh = bm[h];
      float acc = 0.f;
      for (int dd = 0; dd < D; ++dd) {
        float fe = uv[loff[dd] + h] + uv[roff[dd] + h] + bmh;
        acc = fmaf(lm[dd], fmaxf(fe, 0.f), acc);
      }
      float v = acc * inv;
      __hip_bfloat16 hb, lb;
      split_bf16(v, hb, lb);
      cfh[outbase + h] = hb;
      cfl[outbase + h] = lb;
    }
  }
}

// ---------------- root ----------------
__global__ void k_root(const float* __restrict__ chart_p,
                       const __hip_bfloat16* __restrict__ cfh,
                       const __hip_bfloat16* __restrict__ cfl,
                       const float* __restrict__ starts,
                       float* __restrict__ out) {
  __shared__ float red[2];
  int b = blockIdx.x, tid = threadIdx.x; // 128
  long cell = dBase(cL - 1) + b;
  float v = chart_p[cell * cS + tid] * starts[tid];
  #pragma unroll
  for (int off = 1; off < 64; off <<= 1) v += __shfl_xor(v, off, 64);
  if ((tid & 63) == 0) red[tid >> 6] = v;
  __syncthreads();
  float score = red[0] + red[1];
  size_t fbase = (size_t)cell * cSD;
  for (int h = tid; h < cSD; h += 128) {
    float f = __bfloat162float(cfh[fbase + h]) + __bfloat162float(cfl[fbase + h]);
    out[(size_t)b * cSD + h] = f * score;
  }
}

extern "C" void kernel_launch(void* const* d_in, const int* in_sizes, int n_in,
                              void* d_out, int out_size, void* d_ws, size_t ws_size,
                              hipStream_t stream) {
  const int* word = (const int*)d_in[0];
  const float* WE = (const float*)d_in[1];
  const float* preterm = (const float*)d_in[2];
  const float* G = (const float*)d_in[3];
  const float* starts = (const float*)d_in[4];
  const float* Wp = (const float*)d_in[5];
  const float* bp = (const float*)d_in[6];
  const float* Wm = (const float*)d_in[7];
  const float* bm = (const float*)d_in[8];
  float* out = (float*)d_out;
  float* ws = (float*)d_ws;

  size_t off = 0;
  float* chart_p = ws + off; off += (size_t)TRIC * cS;           // 17.3 MB
  float* chart_v = ws + off; off += (size_t)TRIC * cS;           // 17.3 MB
  __hip_bfloat16* cfh = (__hip_bfloat16*)(ws + off); off += (size_t)TRIC * cSD / 2; // 34.6 MB
  __hip_bfloat16* cfl = (__hip_bfloat16*)(ws + off); off += (size_t)TRIC * cSD / 2; // 34.6 MB
  __hip_bfloat16* GllTh = (__hip_bfloat16*)(ws + off); off += (size_t)cNT * cKQ / 2; // 0.5 MB
  __hip_bfloat16* GllTl = (__hip_bfloat16*)(ws + off); off += (size_t)cNT * cKQ / 2;
  __hip_bfloat16* GhhTh = (__hip_bfloat16*)(ws + off); off += (size_t)cNT * cKQ / 2;
  __hip_bfloat16* GhhTl = (__hip_bfloat16*)(ws + off); off += (size_t)cNT * cKQ / 2;
  float* GsumT = ws + off; off += cS * cS;
  float* e_arr = ws + off; off += (size_t)2048 * 4096;           // 33.5 MB
  float* f_arr = ws + off; off += (size_t)2048 * 4096;           // 33.5 MB
  __hip_bfloat16* WmTh = (__hip_bfloat16*)(ws + off); off += (size_t)cSD * 1024 / 2;
  __hip_bfloat16* WmTl = (__hip_bfloat16*)(ws + off); off += (size_t)cSD * 1024 / 2;
  float* uv = ws + off; off += (size_t)TRIC * 1024;              // 138.4 MB packed
  __hip_bfloat16* Oh0 = (__hip_bfloat16*)(ws + off); off += (size_t)CHpad * cKQ / 2; // 16.25 MB
  __hip_bfloat16* Ol0 = (__hip_bfloat16*)(ws + off); off += (size_t)CHpad * cKQ / 2;
  __hip_bfloat16* Oh1 = (__hip_bfloat16*)(ws + off); off += (size_t)CHpad * cKQ / 2;
  __hip_bfloat16* Ol1 = (__hip_bfloat16*)(ws + off); off += (size_t)CHpad * cKQ / 2;
  float* scoresP = ws + off; off += (size_t)CHpad * KS * cNT;    // 8.1 MB
  // total ~388 MB <= 409.6 MB (measured via harness fill WRITE_SIZE)

  auto hdB = [](int d) { return (long)cB * ((long)d * cL - (long)d * (d - 1) / 2); };

  // S1: prep_g(64) || prep_wmt(2048) || diag_p(1024) || feat0(256)
  k_S1<<<64 + 2048 + 1024 + 256, 256, 0, stream>>>(
      G, GllTh, GllTl, GhhTh, GhhTl, GsumT, Wm, WmTh, WmTl, word, preterm,
      chart_p, WE, Wp, bp, cfh, cfl);
  // S2a: prep_e(2048) || prep_f(1024) || diag_v(1024)  [light LDS]
  k_S2a<<<2048 + 1024 + 1024, 256, 0, stream>>>(
      chart_p, G, e_arr, f_arr, GsumT, chart_v);
  // S2b: uv(diag0, 128) || outer(ln=2, 1984) -> Oh0/Ol0  [40KB LDS]
  k_S2b<<<128 + 1984, 256, 0, stream>>>(
      chart_p, cfh, cfl, WmTh, WmTl, uv, Oh0, Ol0);

  for (int ln = 2; ln <= cL; ++ln) {
    int n = cL - ln + 1, Bn = cB * n;
    int useGemm = (ln == 2 || ln >= 4) ? 1 : 0;
    int useEF = (ln >= 3) ? 1 : 0;
    int gx = useGemm ? (Bn + 127) / 128 : 0;
    int sB = gx * KS;
    int Mu = (ln >= 3) ? cB * (cL - (ln - 2)) : 0;    // cells of diag ln-2
    int uB = (ln >= 3) ? ((Mu + 127) / 128) * 8 : 0;
    int oR = (ln >= 3 && ln <= cL - 1) ? cB * (cL - ln) : 0; // rows of diag ln+1
    const __hip_bfloat16* OinH = (ln & 1) ? Oh1 : Oh0;
    const __hip_bfloat16* OinL = (ln & 1) ? Ol1 : Ol0;
    __hip_bfloat16* OoutH = ((ln + 1) & 1) ? Oh1 : Oh0;
    __hip_bfloat16* OoutL = ((ln + 1) & 1) ? Ol1 : Ol0;
    // X(ln): scores(ln) || uv(diag ln-2) || outer(ln+1)
    if (sB + uB + oR > 0)
      k_X<<<sB + uB + oR, 256, 0, stream>>>(
          OinH, OinL, (ln == 2) ? GhhTh : GllTh, (ln == 2) ? GhhTl : GllTl,
          scoresP, gx, Bn, sB,
          cfh, cfl, WmTh, WmTl, uv, hdB(ln - 2), Mu, uB,
          chart_p, OoutH, OoutL, ln + 1, cL - ln, 1, ln - 2);
    // Y(ln): normp(ln) || combine(ln) [h-split only when Bn<=512]
    int hsplit = (Bn <= 512) ? 1 : 0;
    k_Y<<<Bn + (hsplit ? 2 * Bn : Bn), 256, 0, stream>>>(
        scoresP, e_arr, f_arr, GsumT, chart_p, chart_v,
        uv, bm, cfh, cfl, ln, n, useGemm, useEF, Bn, hsplit);
  }

  k_root<<<cB, 128, 0, stream>>>(chart_p, cfh, cfl, starts, out);
}